// Round 1
// baseline (2546.362 us; speedup 1.0000x reference)
//
#include <hip/hip_runtime.h>
#include <hip/hip_bf16.h>
#include <math.h>

// Problem constants (fixed by the reference).
constexpr int Bz = 2;
constexpr int S  = 2048;
constexpr int E  = 1024;
constexpr int NH = 16;
constexpr int DH = 64;          // E / NH
constexpr int E3 = 3 * E;       // 3072

// ---------------------------------------------------------------------------
// GEMM: C[M,N] = A[M,K] @ W[N,:K]^T (+ bias[N]) ; W row n starts at W + n*ldw.
// ACC=true accumulates into C. 64x64 tile, BK=16, 4x4 per thread, 256 threads.
// ---------------------------------------------------------------------------
template<bool ACC>
__global__ __launch_bounds__(256)
void gemm_bt(const float* __restrict__ A, const float* __restrict__ W,
             const float* __restrict__ bias, float* __restrict__ C,
             int M, int N, int K, int ldw)
{
    __shared__ float As[16][68];   // [k][m], +4 pad keeps float4 alignment
    __shared__ float Ws[16][68];   // [k][n]
    const int t  = threadIdx.x;
    const int tx = t & 15;
    const int ty = t >> 4;
    const int m0 = blockIdx.y * 64;
    const int n0 = blockIdx.x * 64;
    const int r  = t >> 2;          // 0..63 row within tile
    const int kq = (t & 3) << 2;    // 0,4,8,12

    float acc[4][4];
    #pragma unroll
    for (int i = 0; i < 4; ++i)
        #pragma unroll
        for (int j = 0; j < 4; ++j) acc[i][j] = 0.f;

    const float* Arow = A + (size_t)(m0 + r) * K   + kq;
    const float* Wrow = W + (size_t)(n0 + r) * ldw + kq;

    for (int k0 = 0; k0 < K; k0 += 16) {
        float4 av = *(const float4*)(Arow + k0);
        float4 wv = *(const float4*)(Wrow + k0);
        __syncthreads();
        As[kq+0][r] = av.x; As[kq+1][r] = av.y; As[kq+2][r] = av.z; As[kq+3][r] = av.w;
        Ws[kq+0][r] = wv.x; Ws[kq+1][r] = wv.y; Ws[kq+2][r] = wv.z; Ws[kq+3][r] = wv.w;
        __syncthreads();
        #pragma unroll
        for (int kk = 0; kk < 16; ++kk) {
            float4 a4 = *(const float4*)&As[kk][ty << 2];
            float4 b4 = *(const float4*)&Ws[kk][tx << 2];
            float a[4] = {a4.x, a4.y, a4.z, a4.w};
            float b[4] = {b4.x, b4.y, b4.z, b4.w};
            #pragma unroll
            for (int i = 0; i < 4; ++i)
                #pragma unroll
                for (int j = 0; j < 4; ++j)
                    acc[i][j] = fmaf(a[i], b[j], acc[i][j]);
        }
    }

    #pragma unroll
    for (int i = 0; i < 4; ++i) {
        const int m = m0 + (ty << 2) + i;
        #pragma unroll
        for (int j = 0; j < 4; ++j) {
            const int n = n0 + (tx << 2) + j;
            float v = acc[i][j];
            if (bias) v += bias[n];
            const size_t idx = (size_t)m * N + n;
            if (ACC) C[idx] += v; else C[idx] = v;
        }
    }
}

// ---------------------------------------------------------------------------
// Global attention (full S keys). Lane-per-query flash:
// block = 256 threads = 4 waves, handles (b, h, 256 queries).
// Each lane owns one query: q[64] and o[64] live in VGPRs; K/V tiles (64x64)
// staged in LDS, read as wave-uniform broadcasts (no bank conflicts, no shfl).
// qkv layout: [B, S, 3E] rows = [q | k | v], head h at cols h*64.
// ---------------------------------------------------------------------------
__global__ __launch_bounds__(256, 1)
void attn_global(const float* __restrict__ qkv, float* __restrict__ outp)
{
    __shared__ float Kt[64][64];
    __shared__ float Vt[64][64];
    const int t    = threadIdx.x;
    const int lane = t & 63;
    const int wave = t >> 6;
    const int blk  = blockIdx.x;          // b*128 + h*8 + qc
    const int qc   = blk & 7;
    const int h    = (blk >> 3) & 15;
    const int b    = blk >> 7;
    const int q    = qc * 256 + wave * 64 + lane;

    const float* qrow = qkv + (size_t)(b * S + q) * E3 + h * DH;
    float qreg[64];
    #pragma unroll
    for (int i = 0; i < 16; ++i) {
        float4 v = *(const float4*)(qrow + i * 4);
        qreg[4*i+0] = v.x * 0.125f;   // dh^-0.5 = 1/8
        qreg[4*i+1] = v.y * 0.125f;
        qreg[4*i+2] = v.z * 0.125f;
        qreg[4*i+3] = v.w * 0.125f;
    }
    float o[64];
    #pragma unroll
    for (int d = 0; d < 64; ++d) o[d] = 0.f;
    float m = -INFINITY, l = 0.f;

    const float* kbase = qkv + (size_t)b * S * E3 + E  + h * DH;
    const float* vbase = qkv + (size_t)b * S * E3 + 2*E + h * DH;

    const int row = t >> 4;          // 0..15
    const int dq  = (t & 15) << 2;   // 0..60

    for (int kt = 0; kt < S / 64; ++kt) {
        __syncthreads();
        #pragma unroll
        for (int i = 0; i < 4; ++i) {
            const int rr = row + i * 16;
            const size_t off = (size_t)(kt * 64 + rr) * E3 + dq;
            *(float4*)&Kt[rr][dq] = *(const float4*)(kbase + off);
            *(float4*)&Vt[rr][dq] = *(const float4*)(vbase + off);
        }
        __syncthreads();
        for (int j = 0; j < 64; ++j) {
            float4 s4 = make_float4(0.f, 0.f, 0.f, 0.f);
            #pragma unroll
            for (int i = 0; i < 16; ++i) {
                float4 k4 = *(const float4*)&Kt[j][i * 4];
                s4.x = fmaf(qreg[4*i+0], k4.x, s4.x);
                s4.y = fmaf(qreg[4*i+1], k4.y, s4.y);
                s4.z = fmaf(qreg[4*i+2], k4.z, s4.z);
                s4.w = fmaf(qreg[4*i+3], k4.w, s4.w);
            }
            const float s  = (s4.x + s4.y) + (s4.z + s4.w);
            const float mn = fmaxf(m, s);
            const float al = __expf(m - mn);
            const float p  = __expf(s - mn);
            if (al != 1.0f) {             // skip rescale once max settles
                #pragma unroll
                for (int d = 0; d < 64; ++d) o[d] *= al;
                l *= al;
            }
            l += p;
            m = mn;
            #pragma unroll
            for (int i = 0; i < 16; ++i) {
                float4 v4 = *(const float4*)&Vt[j][i * 4];
                o[4*i+0] = fmaf(p, v4.x, o[4*i+0]);
                o[4*i+1] = fmaf(p, v4.y, o[4*i+1]);
                o[4*i+2] = fmaf(p, v4.z, o[4*i+2]);
                o[4*i+3] = fmaf(p, v4.w, o[4*i+3]);
            }
        }
    }

    const float inv = 1.0f / l;
    float* orow = outp + (size_t)(b * S + q) * E + h * DH;
    #pragma unroll
    for (int i = 0; i < 16; ++i) {
        float4 v;
        v.x = o[4*i+0] * inv; v.y = o[4*i+1] * inv;
        v.z = o[4*i+2] * inv; v.w = o[4*i+3] * inv;
        *(float4*)(orow + i * 4) = v;
    }
}

// ---------------------------------------------------------------------------
// Block-local attention (16-key blocks). Wave per query, lane = d (dh=64).
// Two-pass softmax; scores via 6-step shfl_xor wave reduction. Tiny (0.27 GF).
// ---------------------------------------------------------------------------
__global__ __launch_bounds__(256)
void attn_local(const float* __restrict__ qkv, float* __restrict__ outp)
{
    const int t    = threadIdx.x;
    const int lane = t & 63;
    const int gid  = blockIdx.x * 4 + (t >> 6);   // wave id over B*NH*S
    const int q = gid & (S - 1);
    const int h = (gid >> 11) & (NH - 1);
    const int b = gid >> 15;

    const float* base = qkv + (size_t)b * S * E3;
    const float qd = base[(size_t)q * E3 + h * DH + lane] * 0.125f;
    const int j0 = q & ~15;

    float s[16];
    #pragma unroll
    for (int jj = 0; jj < 16; ++jj) {
        const float kd = base[(size_t)(j0 + jj) * E3 + E + h * DH + lane];
        float ps = qd * kd;
        #pragma unroll
        for (int off = 32; off > 0; off >>= 1)
            ps += __shfl_xor(ps, off, 64);
        s[jj] = ps;
    }
    float mx = s[0];
    #pragma unroll
    for (int jj = 1; jj < 16; ++jj) mx = fmaxf(mx, s[jj]);
    float l = 0.f;
    #pragma unroll
    for (int jj = 0; jj < 16; ++jj) { s[jj] = __expf(s[jj] - mx); l += s[jj]; }
    float o = 0.f;
    #pragma unroll
    for (int jj = 0; jj < 16; ++jj) {
        const float vd = base[(size_t)(j0 + jj) * E3 + 2 * E + h * DH + lane];
        o = fmaf(s[jj], vd, o);
    }
    outp[(size_t)(b * S + q) * E + h * DH + lane] = o / l;
}

// ---------------------------------------------------------------------------
extern "C" void kernel_launch(void* const* d_in, const int* in_sizes, int n_in,
                              void* d_out, int out_size, void* d_ws, size_t ws_size,
                              hipStream_t stream)
{
    const float* x       = (const float*)d_in[0];
    const float* w_in_g  = (const float*)d_in[1];
    const float* b_in_g  = (const float*)d_in[2];
    const float* w_out_g = (const float*)d_in[3];
    const float* b_out_g = (const float*)d_in[4];
    const float* w_in_l  = (const float*)d_in[5];
    const float* b_in_l  = (const float*)d_in[6];
    const float* w_out_l = (const float*)d_in[7];
    const float* b_out_l = (const float*)d_in[8];
    const float* w_f     = (const float*)d_in[9];
    const float* b_f     = (const float*)d_in[10];
    float* out = (float*)d_out;

    // Workspace (reused across the two branches): qkv 50.3MB + attn 16.8MB + proj 16.8MB
    float* ws_qkv  = (float*)d_ws;                    // [4096, 3072]
    float* ws_attn = ws_qkv  + (size_t)Bz * S * E3;   // [4096, 1024]
    float* ws_proj = ws_attn + (size_t)Bz * S * E;    // [4096, 1024]

    const int M = Bz * S;   // 4096
    dim3 blk(256);

    // ---- global branch ----
    gemm_bt<false><<<dim3(E3 / 64, M / 64), blk, 0, stream>>>(x, w_in_g, b_in_g, ws_qkv, M, E3, E, E);
    attn_global<<<dim3(Bz * NH * (S / 256)), blk, 0, stream>>>(ws_qkv, ws_attn);
    gemm_bt<false><<<dim3(E / 64, M / 64), blk, 0, stream>>>(ws_attn, w_out_g, b_out_g, ws_proj, M, E, E, E);
    // out = g_proj @ w_f[:, :E]^T + b_f
    gemm_bt<false><<<dim3(E / 64, M / 64), blk, 0, stream>>>(ws_proj, w_f, b_f, out, M, E, E, 2 * E);

    // ---- local branch ----
    gemm_bt<false><<<dim3(E3 / 64, M / 64), blk, 0, stream>>>(x, w_in_l, b_in_l, ws_qkv, M, E3, E, E);
    attn_local<<<dim3(Bz * NH * S / 4), blk, 0, stream>>>(ws_qkv, ws_attn);
    gemm_bt<false><<<dim3(E / 64, M / 64), blk, 0, stream>>>(ws_attn, w_out_l, b_out_l, ws_proj, M, E, E, E);
    // out += l_proj @ w_f[:, E:]^T
    gemm_bt<true><<<dim3(E / 64, M / 64), blk, 0, stream>>>(ws_proj, w_f + E, nullptr, out, M, E, E, 2 * E);
}

// Round 3
// 1075.124 us; speedup vs baseline: 2.3684x; 2.3684x over previous
//
#include <hip/hip_runtime.h>
#include <hip/hip_bf16.h>
#include <math.h>
#include <stdint.h>

// Problem constants (fixed by the reference).
constexpr int Bz = 2;
constexpr int S  = 2048;
constexpr int E  = 1024;
constexpr int NH = 16;
constexpr int DH = 64;
constexpr int E3 = 3 * E;       // 3072
constexpr int NSPLIT = 4;       // key-dim splits for global attention
constexpr int KT_PER_SPLIT = (S / NSPLIT) / 64;   // 8 tiles of 64 keys

typedef __attribute__((ext_vector_type(8))) short short8;      // MFMA A/B frag (8 bf16)
typedef __attribute__((ext_vector_type(4))) float f32x4;       // MFMA C/D frag
typedef __attribute__((ext_vector_type(8))) unsigned short bf16x8;
typedef __attribute__((ext_vector_type(4))) unsigned short bf16x4;

__device__ __forceinline__ float bf2f(unsigned short u) {
    union { unsigned int i; float f; } c; c.i = ((unsigned int)u) << 16; return c.f;
}
__device__ __forceinline__ unsigned short f2bf(float f) {   // round-to-nearest-even
    union { float f; unsigned int i; } c; c.f = f;
    unsigned int r = c.i + 0x7fffu + ((c.i >> 16) & 1u);
    return (unsigned short)(r >> 16);
}

#define GLD_LDS(g, l) __builtin_amdgcn_global_load_lds( \
    (const __attribute__((address_space(1))) void*)(g), \
    (__attribute__((address_space(3))) void*)(l), 16, 0, 0)

// ---------------------------------------------------------------------------
// fp32 -> bf16 conversion, 4 elems/thread. n must be a multiple of 4.
// ---------------------------------------------------------------------------
__global__ __launch_bounds__(256)
void cvt_f2b(const float* __restrict__ src, unsigned short* __restrict__ dst, int n)
{
    const int i = (blockIdx.x * 256 + threadIdx.x) * 4;
    if (i >= n) return;
    float4 v = *(const float4*)(src + i);
    bf16x4 o = { f2bf(v.x), f2bf(v.y), f2bf(v.z), f2bf(v.w) };
    *(bf16x4*)(dst + i) = o;
}

// ---------------------------------------------------------------------------
// bf16 MFMA GEMM: C[M,N] = A[M,K] @ W[N,:K]^T (+ bias), W row n at W + n*ldw.
// 128x128 tile, BK=32, 256 thr = 4 waves (2x2), each wave 64x64 via 4x4 grid
// of 16x16x32 MFMA. global_load_lds width-16 staging (contiguous LDS, no pad).
// A-frag / B-frag: lane holds row (lane&15), k = (lane>>4)*8..+7 -> one b128.
// C/D: col = lane&15, row = (lane>>4)*4 + reg   [verified m89/m91].
// OutT: float or bf16(unsigned short). ACC accumulates (float only).
// ---------------------------------------------------------------------------
template<typename OutT, bool ACC>
__global__ __launch_bounds__(256)
void gemm_mfma(const unsigned short* __restrict__ A, const unsigned short* __restrict__ W,
               const float* __restrict__ bias, OutT* __restrict__ C,
               int M, int N, int K, int ldw)
{
    __shared__ __align__(16) short As[128 * 32];   // [row][k] row-major, 8 KB
    __shared__ __align__(16) short Bs[128 * 32];
    const int t = threadIdx.x;
    const int lane = t & 63, wave = t >> 6;
    const int wm = wave & 1, wn = wave >> 1;
    const int m0 = blockIdx.y * 128, n0 = blockIdx.x * 128;
    const int lm = lane & 15, lk = lane >> 4;

    f32x4 acc[4][4] = {};

    // staging chunks: 512 x 16B per tile, thread t does chunks t and t+256
    const int c1 = t, c2 = t + 256;
    const int r1 = c1 >> 2, kg1 = (c1 & 3) * 8;
    const int r2 = c2 >> 2, kg2 = (c2 & 3) * 8;
    const unsigned short* a1 = A + (size_t)(m0 + r1) * K + kg1;
    const unsigned short* a2 = A + (size_t)(m0 + r2) * K + kg2;
    const unsigned short* w1 = W + (size_t)(n0 + r1) * ldw + kg1;
    const unsigned short* w2 = W + (size_t)(n0 + r2) * ldw + kg2;
    // wave-uniform LDS bases (lane offset is implicit: +lane*16B)
    short* ldsA1 = As + (wave * 64) * 8;
    short* ldsA2 = As + (wave * 64 + 256) * 8;
    short* ldsB1 = Bs + (wave * 64) * 8;
    short* ldsB2 = Bs + (wave * 64 + 256) * 8;

    for (int k0 = 0; k0 < K; k0 += 32) {
        __syncthreads();                   // previous iter's reads done
        GLD_LDS(a1 + k0, ldsA1);
        GLD_LDS(a2 + k0, ldsA2);
        GLD_LDS(w1 + k0, ldsB1);
        GLD_LDS(w2 + k0, ldsB2);
        __syncthreads();                   // drains vmcnt before barrier

        short8 af[4], bfr[4];
        #pragma unroll
        for (int i = 0; i < 4; ++i)
            af[i] = *(const short8*)&As[(wm * 64 + i * 16 + lm) * 32 + lk * 8];
        #pragma unroll
        for (int j = 0; j < 4; ++j)
            bfr[j] = *(const short8*)&Bs[(wn * 64 + j * 16 + lm) * 32 + lk * 8];
        #pragma unroll
        for (int i = 0; i < 4; ++i)
            #pragma unroll
            for (int j = 0; j < 4; ++j)
                acc[i][j] = __builtin_amdgcn_mfma_f32_16x16x32_bf16(af[i], bfr[j], acc[i][j], 0, 0, 0);
    }

    #pragma unroll
    for (int i = 0; i < 4; ++i) {
        #pragma unroll
        for (int j = 0; j < 4; ++j) {
            const int nn = n0 + wn * 64 + j * 16 + lm;
            const float bv = bias ? bias[nn] : 0.f;
            #pragma unroll
            for (int r = 0; r < 4; ++r) {
                const int mm = m0 + wm * 64 + i * 16 + lk * 4 + r;
                const float v = acc[i][j][r] + bv;
                const size_t idx = (size_t)mm * N + nn;
                if constexpr (ACC)                    C[idx] += v;
                else if constexpr (sizeof(OutT) == 2) ((unsigned short*)C)[idx] = f2bf(v);
                else                                  C[idx] = v;
            }
        }
    }
}

// ---------------------------------------------------------------------------
// Global attention, split-K flash partials. Lane-per-query (fp32 math),
// block = 256 thr = 4 waves = 256 queries of one (b,h); processes 512 keys
// (one split). Writes unnormalized o (bf16) + per-query (m, l) fp32.
// Grid = B*NH*8*NSPLIT = 1024 blocks -> ~3-4 blocks/CU (vs 1 before).
// ---------------------------------------------------------------------------
__global__ __launch_bounds__(256)
void attn_global_part(const unsigned short* __restrict__ qkv,
                      unsigned short* __restrict__ opart, float* __restrict__ ml)
{
    __shared__ float Kt[64][64];
    __shared__ float Vt[64][64];
    const int t = threadIdx.x, lane = t & 63, wave = t >> 6;
    const int blk   = blockIdx.x;
    const int split = blk & 3;
    const int qc    = (blk >> 2) & 7;
    const int h     = (blk >> 5) & 15;
    const int b     = blk >> 9;
    const int q     = qc * 256 + wave * 64 + lane;

    const unsigned short* qrow = qkv + (size_t)(b * S + q) * E3 + h * DH;
    float qreg[64];
    #pragma unroll
    for (int i = 0; i < 8; ++i) {
        bf16x8 v = *(const bf16x8*)(qrow + i * 8);
        #pragma unroll
        for (int j = 0; j < 8; ++j) qreg[i * 8 + j] = bf2f(v[j]) * 0.125f;  // dh^-0.5
    }
    float o[64];
    #pragma unroll
    for (int d = 0; d < 64; ++d) o[d] = 0.f;
    float m = -INFINITY, l = 0.f;

    const unsigned short* kbase = qkv + (size_t)b * S * E3 + E     + h * DH;
    const unsigned short* vbase = qkv + (size_t)b * S * E3 + 2 * E + h * DH;

    // staging: 64x64 bf16 per tensor = 512 chunks of 8; thread does 2 per tensor
    const int c1 = t, c2 = t + 256;
    const int r1 = c1 >> 3, col1 = (c1 & 7) * 8;
    const int r2 = c2 >> 3, col2 = (c2 & 7) * 8;

    for (int kt = split * KT_PER_SPLIT; kt < (split + 1) * KT_PER_SPLIT; ++kt) {
        __syncthreads();
        {
            const size_t off1 = (size_t)(kt * 64 + r1) * E3 + col1;
            const size_t off2 = (size_t)(kt * 64 + r2) * E3 + col2;
            bf16x8 k1 = *(const bf16x8*)(kbase + off1);
            bf16x8 v1 = *(const bf16x8*)(vbase + off1);
            bf16x8 k2 = *(const bf16x8*)(kbase + off2);
            bf16x8 v2 = *(const bf16x8*)(vbase + off2);
            #pragma unroll
            for (int j = 0; j < 8; ++j) {
                Kt[r1][col1 + j] = bf2f(k1[j]);
                Vt[r1][col1 + j] = bf2f(v1[j]);
                Kt[r2][col2 + j] = bf2f(k2[j]);
                Vt[r2][col2 + j] = bf2f(v2[j]);
            }
        }
        __syncthreads();
        for (int j = 0; j < 64; ++j) {
            float4 s4 = make_float4(0.f, 0.f, 0.f, 0.f);
            #pragma unroll
            for (int i = 0; i < 16; ++i) {
                float4 k4 = *(const float4*)&Kt[j][i * 4];
                s4.x = fmaf(qreg[4*i+0], k4.x, s4.x);
                s4.y = fmaf(qreg[4*i+1], k4.y, s4.y);
                s4.z = fmaf(qreg[4*i+2], k4.z, s4.z);
                s4.w = fmaf(qreg[4*i+3], k4.w, s4.w);
            }
            const float s  = (s4.x + s4.y) + (s4.z + s4.w);
            const float mn = fmaxf(m, s);
            const float al = __expf(m - mn);
            const float p  = __expf(s - mn);
            if (al != 1.0f) {
                #pragma unroll
                for (int d = 0; d < 64; ++d) o[d] *= al;
                l *= al;
            }
            l += p;
            m = mn;
            #pragma unroll
            for (int i = 0; i < 16; ++i) {
                float4 v4 = *(const float4*)&Vt[j][i * 4];
                o[4*i+0] = fmaf(p, v4.x, o[4*i+0]);
                o[4*i+1] = fmaf(p, v4.y, o[4*i+1]);
                o[4*i+2] = fmaf(p, v4.z, o[4*i+2]);
                o[4*i+3] = fmaf(p, v4.w, o[4*i+3]);
            }
        }
    }

    const size_t pbase = ((((size_t)split * Bz + b) * NH + h) * S + q) * 64;
    #pragma unroll
    for (int i = 0; i < 8; ++i) {
        bf16x8 ov;
        #pragma unroll
        for (int j = 0; j < 8; ++j) ov[j] = f2bf(o[i * 8 + j]);
        *(bf16x8*)(opart + pbase + i * 8) = ov;
    }
    const size_t mlb = ((((size_t)split * Bz + b) * NH + h) * S + q) * 2;
    ml[mlb]     = m;
    ml[mlb + 1] = l;
}

// ---------------------------------------------------------------------------
// Merge NSPLIT partials -> normalized attention output (bf16, [B,S,E] layout).
// One thread per (b,h,q,d). Memory-bound (~36 MB read, 8 MB write).
// ---------------------------------------------------------------------------
__global__ __launch_bounds__(256)
void attn_merge(const unsigned short* __restrict__ opart, const float* __restrict__ ml,
                unsigned short* __restrict__ attn)
{
    const int id = blockIdx.x * 256 + threadIdx.x;   // B*NH*S*64 = 4,194,304
    const int d = id & 63;
    const int h = (id >> 6) & 15;
    const int q = (id >> 10) & 2047;
    const int b = id >> 21;

    float mi[NSPLIT], li[NSPLIT], mM = -INFINITY;
    #pragma unroll
    for (int s = 0; s < NSPLIT; ++s) {
        const size_t x = ((((size_t)s * Bz + b) * NH + h) * S + q) * 2;
        mi[s] = ml[x]; li[s] = ml[x + 1];
        mM = fmaxf(mM, mi[s]);
    }
    float L = 0.f, acc = 0.f;
    #pragma unroll
    for (int s = 0; s < NSPLIT; ++s) {
        const float sc = __expf(mi[s] - mM);
        L += sc * li[s];
        acc += sc * bf2f(opart[((((size_t)s * Bz + b) * NH + h) * S + q) * 64 + d]);
    }
    attn[(size_t)(b * S + q) * E + h * 64 + d] = f2bf(acc / L);
}

// ---------------------------------------------------------------------------
// Block-local attention (16-key blocks), bf16 in/out. Wave per query, lane = d.
// ---------------------------------------------------------------------------
__global__ __launch_bounds__(256)
void attn_local(const unsigned short* __restrict__ qkv, unsigned short* __restrict__ outp)
{
    const int t = threadIdx.x, lane = t & 63;
    const int gid = blockIdx.x * 4 + (t >> 6);       // wave id over B*NH*S
    const int q = gid & (S - 1);
    const int h = (gid >> 11) & (NH - 1);
    const int b = gid >> 15;

    const unsigned short* base = qkv + (size_t)b * S * E3;
    const float qd = bf2f(base[(size_t)q * E3 + h * DH + lane]) * 0.125f;
    const int j0 = q & ~15;

    float s[16];
    #pragma unroll
    for (int jj = 0; jj < 16; ++jj) {
        const float kd = bf2f(base[(size_t)(j0 + jj) * E3 + E + h * DH + lane]);
        float ps = qd * kd;
        #pragma unroll
        for (int off = 32; off > 0; off >>= 1)
            ps += __shfl_xor(ps, off, 64);
        s[jj] = ps;
    }
    float mx = s[0];
    #pragma unroll
    for (int jj = 1; jj < 16; ++jj) mx = fmaxf(mx, s[jj]);
    float l = 0.f;
    #pragma unroll
    for (int jj = 0; jj < 16; ++jj) { s[jj] = __expf(s[jj] - mx); l += s[jj]; }
    float o = 0.f;
    #pragma unroll
    for (int jj = 0; jj < 16; ++jj) {
        const float vd = bf2f(base[(size_t)(j0 + jj) * E3 + 2 * E + h * DH + lane]);
        o = fmaf(s[jj], vd, o);
    }
    outp[(size_t)(b * S + q) * E + h * DH + lane] = f2bf(o / l);
}

// ---------------------------------------------------------------------------
extern "C" void kernel_launch(void* const* d_in, const int* in_sizes, int n_in,
                              void* d_out, int out_size, void* d_ws, size_t ws_size,
                              hipStream_t stream)
{
    const float* x       = (const float*)d_in[0];
    const float* w_in_g  = (const float*)d_in[1];
    const float* b_in_g  = (const float*)d_in[2];
    const float* w_out_g = (const float*)d_in[3];
    const float* b_out_g = (const float*)d_in[4];
    const float* w_in_l  = (const float*)d_in[5];
    const float* b_in_l  = (const float*)d_in[6];
    const float* w_out_l = (const float*)d_in[7];
    const float* b_out_l = (const float*)d_in[8];
    const float* w_f     = (const float*)d_in[9];
    const float* b_f     = (const float*)d_in[10];
    float* out = (float*)d_out;

    // workspace carve-up (~102 MB total)
    char* p = (char*)d_ws;
    unsigned short* qkv_b   = (unsigned short*)p; p += (size_t)4096 * 3072 * 2;
    unsigned short* xb      = (unsigned short*)p; p += (size_t)4096 * 1024 * 2;
    unsigned short* attn_b  = (unsigned short*)p; p += (size_t)4096 * 1024 * 2;
    unsigned short* proj_b  = (unsigned short*)p; p += (size_t)4096 * 1024 * 2;
    unsigned short* wing_b  = (unsigned short*)p; p += (size_t)3072 * 1024 * 2;
    unsigned short* woutg_b = (unsigned short*)p; p += (size_t)1024 * 1024 * 2;
    unsigned short* winl_b  = (unsigned short*)p; p += (size_t)3072 * 1024 * 2;
    unsigned short* woutl_b = (unsigned short*)p; p += (size_t)1024 * 1024 * 2;
    unsigned short* wf_b    = (unsigned short*)p; p += (size_t)1024 * 2048 * 2;
    unsigned short* opart   = (unsigned short*)p; p += (size_t)NSPLIT * Bz * NH * S * 64 * 2;
    float*          mlbuf   = (float*)p;          p += (size_t)NSPLIT * Bz * NH * S * 2 * 4;

    dim3 blk(256);
    auto cvt = [&](const float* s, unsigned short* d, int n) {
        cvt_f2b<<<dim3(n / 1024), blk, 0, stream>>>(s, d, n);
    };
    cvt(x,       xb,      4096 * 1024);
    cvt(w_in_g,  wing_b,  3072 * 1024);
    cvt(w_out_g, woutg_b, 1024 * 1024);
    cvt(w_in_l,  winl_b,  3072 * 1024);
    cvt(w_out_l, woutl_b, 1024 * 1024);
    cvt(w_f,     wf_b,    1024 * 2048);

    const int M = Bz * S;   // 4096

    // ---- global branch ----
    gemm_mfma<unsigned short, false><<<dim3(3072/128, M/128), blk, 0, stream>>>(
        xb, wing_b, b_in_g, qkv_b, M, 3072, 1024, 1024);
    attn_global_part<<<dim3(Bz * NH * 8 * NSPLIT), blk, 0, stream>>>(qkv_b, opart, mlbuf);
    attn_merge<<<dim3(Bz * NH * S * 64 / 256), blk, 0, stream>>>(opart, mlbuf, attn_b);
    gemm_mfma<unsigned short, false><<<dim3(1024/128, M/128), blk, 0, stream>>>(
        attn_b, woutg_b, b_out_g, proj_b, M, 1024, 1024, 1024);
    gemm_mfma<float, false><<<dim3(1024/128, M/128), blk, 0, stream>>>(
        proj_b, wf_b, b_f, out, M, 1024, 1024, 2048);

    // ---- local branch ----
    gemm_mfma<unsigned short, false><<<dim3(3072/128, M/128), blk, 0, stream>>>(
        xb, winl_b, b_in_l, qkv_b, M, 3072, 1024, 1024);
    attn_local<<<dim3(Bz * NH * S / 4), blk, 0, stream>>>(qkv_b, attn_b);
    gemm_mfma<unsigned short, false><<<dim3(1024/128, M/128), blk, 0, stream>>>(
        attn_b, woutl_b, b_out_l, proj_b, M, 1024, 1024, 1024);
    gemm_mfma<float, true><<<dim3(1024/128, M/128), blk, 0, stream>>>(
        proj_b, wf_b + 1024, nullptr, out, M, 1024, 1024, 2048);
}

// Round 4
// 504.557 us; speedup vs baseline: 5.0467x; 2.1308x over previous
//
#include <hip/hip_runtime.h>
#include <hip/hip_bf16.h>
#include <math.h>
#include <stdint.h>

// Problem constants (fixed by the reference).
constexpr int Bz = 2;
constexpr int S  = 2048;
constexpr int E  = 1024;
constexpr int NH = 16;
constexpr int DH = 64;
constexpr int E3 = 3 * E;       // 3072

typedef __attribute__((ext_vector_type(8))) short short8;      // MFMA A/B frag (8 bf16)
typedef __attribute__((ext_vector_type(4))) float f32x4;       // MFMA C/D frag
typedef __attribute__((ext_vector_type(8))) unsigned short bf16x8;
typedef __attribute__((ext_vector_type(4))) unsigned short bf16x4;

__device__ __forceinline__ float bf2f(unsigned short u) {
    union { unsigned int i; float f; } c; c.i = ((unsigned int)u) << 16; return c.f;
}
__device__ __forceinline__ unsigned short f2bf(float f) {   // round-to-nearest-even
    union { float f; unsigned int i; } c; c.f = f;
    unsigned int r = c.i + 0x7fffu + ((c.i >> 16) & 1u);
    return (unsigned short)(r >> 16);
}

#define GLD_LDS(g, l) __builtin_amdgcn_global_load_lds( \
    (const __attribute__((address_space(1))) void*)(g), \
    (__attribute__((address_space(3))) void*)(l), 16, 0, 0)

// ---------------------------------------------------------------------------
// fp32 -> bf16 conversion, 4 elems/thread.
// ---------------------------------------------------------------------------
__global__ __launch_bounds__(256)
void cvt_f2b(const float* __restrict__ src, unsigned short* __restrict__ dst, int n)
{
    const int i = (blockIdx.x * 256 + threadIdx.x) * 4;
    if (i >= n) return;
    float4 v = *(const float4*)(src + i);
    bf16x4 o = { f2bf(v.x), f2bf(v.y), f2bf(v.z), f2bf(v.w) };
    *(bf16x4*)(dst + i) = o;
}

// ---------------------------------------------------------------------------
// bf16 MFMA GEMM (m97 structure): C[M,N] = A[M,K] @ W[N,:K]^T (+ bias).
// 128x128 tile, BK=32, 4 waves 2x2, 4x4 16x16x32 MFMA per wave. Verified R3.
// ---------------------------------------------------------------------------
template<typename OutT, bool ACC>
__global__ __launch_bounds__(256)
void gemm_mfma(const unsigned short* __restrict__ A, const unsigned short* __restrict__ W,
               const float* __restrict__ bias, OutT* __restrict__ C,
               int M, int N, int K, int ldw)
{
    __shared__ __align__(16) short As[128 * 32];
    __shared__ __align__(16) short Bs[128 * 32];
    const int t = threadIdx.x;
    const int lane = t & 63, wave = t >> 6;
    const int wm = wave & 1, wn = wave >> 1;
    const int m0 = blockIdx.y * 128, n0 = blockIdx.x * 128;
    const int lm = lane & 15, lk = lane >> 4;

    f32x4 acc[4][4] = {};

    const int c1 = t, c2 = t + 256;
    const int r1 = c1 >> 2, kg1 = (c1 & 3) * 8;
    const int r2 = c2 >> 2, kg2 = (c2 & 3) * 8;
    const unsigned short* a1 = A + (size_t)(m0 + r1) * K + kg1;
    const unsigned short* a2 = A + (size_t)(m0 + r2) * K + kg2;
    const unsigned short* w1 = W + (size_t)(n0 + r1) * ldw + kg1;
    const unsigned short* w2 = W + (size_t)(n0 + r2) * ldw + kg2;
    short* ldsA1 = As + (wave * 64) * 8;
    short* ldsA2 = As + (wave * 64 + 256) * 8;
    short* ldsB1 = Bs + (wave * 64) * 8;
    short* ldsB2 = Bs + (wave * 64 + 256) * 8;

    for (int k0 = 0; k0 < K; k0 += 32) {
        __syncthreads();
        GLD_LDS(a1 + k0, ldsA1);
        GLD_LDS(a2 + k0, ldsA2);
        GLD_LDS(w1 + k0, ldsB1);
        GLD_LDS(w2 + k0, ldsB2);
        __syncthreads();

        short8 af[4], bfr[4];
        #pragma unroll
        for (int i = 0; i < 4; ++i)
            af[i] = *(const short8*)&As[(wm * 64 + i * 16 + lm) * 32 + lk * 8];
        #pragma unroll
        for (int j = 0; j < 4; ++j)
            bfr[j] = *(const short8*)&Bs[(wn * 64 + j * 16 + lm) * 32 + lk * 8];
        #pragma unroll
        for (int i = 0; i < 4; ++i)
            #pragma unroll
            for (int j = 0; j < 4; ++j)
                acc[i][j] = __builtin_amdgcn_mfma_f32_16x16x32_bf16(af[i], bfr[j], acc[i][j], 0, 0, 0);
    }

    #pragma unroll
    for (int i = 0; i < 4; ++i) {
        #pragma unroll
        for (int j = 0; j < 4; ++j) {
            const int nn = n0 + wn * 64 + j * 16 + lm;
            const float bv = bias ? bias[nn] : 0.f;
            #pragma unroll
            for (int r = 0; r < 4; ++r) {
                const int mm = m0 + wm * 64 + i * 16 + lk * 4 + r;
                const float v = acc[i][j][r] + bv;
                const size_t idx = (size_t)mm * N + nn;
                if constexpr (ACC)                    C[idx] += v;
                else if constexpr (sizeof(OutT) == 2) ((unsigned short*)C)[idx] = f2bf(v);
                else                                  C[idx] = v;
            }
        }
    }
}

// ---------------------------------------------------------------------------
// V transpose: qkv V slice [b][s][2E + h*64 + d] -> vt[(b*NH+h)*64 + d][s].
// One block per (b, h, 64-key tile); LDS tile transpose, coalesced both ways.
// ---------------------------------------------------------------------------
__global__ __launch_bounds__(256)
void vt_transpose(const unsigned short* __restrict__ qkv, unsigned short* __restrict__ vt)
{
    __shared__ unsigned short Ts[64][66];   // [d][key], +2 pad breaks bank alias
    const int t = threadIdx.x;
    const int bid = blockIdx.x;             // b*512 + h*32 + st
    const int st = bid & 31;
    const int h  = (bid >> 5) & 15;
    const int b  = bid >> 9;
    const int s0 = st * 64;

    #pragma unroll
    for (int r = 0; r < 2; ++r) {
        const int c = r * 256 + t;
        const int key = c >> 3, dg = c & 7;
        bf16x8 v = *(const bf16x8*)(qkv + ((size_t)(b * S) + s0 + key) * E3 + 2 * E + h * 64 + dg * 8);
        #pragma unroll
        for (int j = 0; j < 8; ++j) Ts[dg * 8 + j][key] = v[j];
    }
    __syncthreads();
    #pragma unroll
    for (int r = 0; r < 2; ++r) {
        const int c = r * 256 + t;
        const int d = c >> 3, kg = c & 7;
        bf16x8 o;
        #pragma unroll
        for (int j = 0; j < 8; ++j) o[j] = Ts[d][kg * 8 + j];
        *(bf16x8*)(vt + ((size_t)(b * NH + h) * 64 + d) * S + s0 + kg * 8) = o;
    }
}

// ---------------------------------------------------------------------------
// MFMA flash attention (global branch). Block = 4 waves = 64 queries of one
// (b,h); wave owns 16 q-rows. Loop over 32 key-tiles of 64:
//   S = Q K^T via mfma (Q A-frags from global, K B-frags from LDS [kk][key][32]),
//   online softmax in C-layout regs (row = lk*4+reg, col-lanes = lm,
//   reductions via shfl_xor 1/2/4/8), P -> per-wave LDS (xor-swizzled) ->
//   A-frags, V B-frags from LDS [kk][d][32key] (staged from pre-transposed vt),
//   O += P V with per-row alpha rescale. Layouts per m89/m91/m97.
// ---------------------------------------------------------------------------
__global__ __launch_bounds__(256, 2)
void attn_flash(const unsigned short* __restrict__ qkv,
                const unsigned short* __restrict__ vt,
                unsigned short* __restrict__ attn)
{
    __shared__ __align__(16) unsigned short Ks[2][64][32];   // [kk][key][d']   8 KB
    __shared__ __align__(16) unsigned short Vs[2][64][32];   // [kk][d][key']   8 KB
    __shared__ __align__(16) unsigned short Ps[4][2][16][32];// [wave][kk][m][col_sw] 8 KB

    const int t = threadIdx.x, lane = t & 63, wq = t >> 6;
    const int lm = lane & 15, lk = lane >> 4;
    const int bid = blockIdx.x;              // b*512 + h*32 + qb
    const int qb = bid & 31;
    const int h  = (bid >> 5) & 15;
    const int b  = bid >> 9;
    const int q0 = qb * 64 + wq * 16;        // wave's first query row

    // Q A-frags, pre-scaled by dh^-0.5 = 1/8 (exact power-of-2 in bf16).
    short8 qf[2];
    {
        const unsigned short* qrow = qkv + ((size_t)(b * S) + q0 + lm) * E3 + h * DH;
        #pragma unroll
        for (int kk = 0; kk < 2; ++kk) {
            bf16x8 v = *(const bf16x8*)(qrow + kk * 32 + lk * 8);
            #pragma unroll
            for (int j = 0; j < 8; ++j)
                ((unsigned short*)&qf[kk])[j] = f2bf(bf2f(v[j]) * 0.125f);
        }
    }

    // Staging chunk decode (two GLD_LDS per tensor per thread; chunk c = r*256 + wq*64 + lane).
    const int idx0 = (wq * 64 + lane) & 255;        // r=0 -> kk=0 ; r=1 -> kk=1
    const int row0 = idx0 >> 2, g0 = (idx0 & 3) * 8;
    const unsigned short* kg[2];
    const unsigned short* vg[2];
    #pragma unroll
    for (int r = 0; r < 2; ++r) {
        kg[r] = qkv + ((size_t)(b * S) + row0) * E3 + E + h * 64 + r * 32 + g0;   // [key][d]
        vg[r] = vt + ((size_t)(b * NH + h) * 64 + row0) * S + r * 32 + g0;        // [d][key]
    }
    unsigned short* kl[2] = { &Ks[0][0][0] + (wq * 64) * 8, &Ks[0][0][0] + (256 + wq * 64) * 8 };
    unsigned short* vl[2] = { &Vs[0][0][0] + (wq * 64) * 8, &Vs[0][0][0] + (256 + wq * 64) * 8 };

    f32x4 O[4] = {};
    float mreg[4] = { -INFINITY, -INFINITY, -INFINITY, -INFINITY };
    float lreg[4] = { 0.f, 0.f, 0.f, 0.f };
    const int psw = (lk ^ ((lm >> 2) & 3)) * 8;     // swizzled A-frag read col

    for (int kt = 0; kt < S / 64; ++kt) {
        __syncthreads();                            // prior tile's K/V reads done
        GLD_LDS(kg[0] + (size_t)kt * 64 * E3, kl[0]);
        GLD_LDS(kg[1] + (size_t)kt * 64 * E3, kl[1]);
        GLD_LDS(vg[0] + kt * 64, vl[0]);
        GLD_LDS(vg[1] + kt * 64, vl[1]);
        __syncthreads();                            // vmcnt drained before use

        // S = Q K^T : 8 MFMA
        f32x4 sfr[4] = {};
        #pragma unroll
        for (int jn = 0; jn < 4; ++jn) {
            #pragma unroll
            for (int kk = 0; kk < 2; ++kk) {
                short8 kf = *(const short8*)&Ks[kk][jn * 16 + lm][lk * 8];
                sfr[jn] = __builtin_amdgcn_mfma_f32_16x16x32_bf16(qf[kk], kf, sfr[jn], 0, 0, 0);
            }
        }

        // online softmax (rows = lk*4+reg, cols across lm lanes)
        float rmax[4], alpha[4], rsum[4];
        #pragma unroll
        for (int g = 0; g < 4; ++g)
            rmax[g] = fmaxf(fmaxf(sfr[0][g], sfr[1][g]), fmaxf(sfr[2][g], sfr[3][g]));
        #pragma unroll
        for (int off = 8; off >= 1; off >>= 1)
            #pragma unroll
            for (int g = 0; g < 4; ++g)
                rmax[g] = fmaxf(rmax[g], __shfl_xor(rmax[g], off, 64));
        #pragma unroll
        for (int g = 0; g < 4; ++g) {
            const float mn = fmaxf(mreg[g], rmax[g]);
            alpha[g] = __expf(mreg[g] - mn);
            mreg[g] = mn;
            rsum[g] = 0.f;
        }
        #pragma unroll
        for (int jn = 0; jn < 4; ++jn)
            #pragma unroll
            for (int g = 0; g < 4; ++g) {
                const float p = __expf(sfr[jn][g] - mreg[g]);
                sfr[jn][g] = p;
                rsum[g] += p;
            }
        #pragma unroll
        for (int off = 8; off >= 1; off >>= 1)
            #pragma unroll
            for (int g = 0; g < 4; ++g)
                rsum[g] += __shfl_xor(rsum[g], off, 64);
        #pragma unroll
        for (int g = 0; g < 4; ++g)
            lreg[g] = lreg[g] * alpha[g] + rsum[g];

        // P -> wave-private LDS (xor-swizzle 8-groups: g ^= row>>2)
        #pragma unroll
        for (int jn = 0; jn < 4; ++jn) {
            const int gsw = ((((jn & 1) << 1) | (lm >> 3)) ^ lk) * 8 + (lm & 7);
            #pragma unroll
            for (int g = 0; g < 4; ++g)
                Ps[wq][jn >> 1][lk * 4 + g][gsw] = f2bf(sfr[jn][g]);
        }

        // rescale O, then O += P V : 8 MFMA
        #pragma unroll
        for (int jd = 0; jd < 4; ++jd)
            #pragma unroll
            for (int g = 0; g < 4; ++g)
                O[jd][g] *= alpha[g];

        short8 pf[2];
        pf[0] = *(const short8*)&Ps[wq][0][lm][psw];
        pf[1] = *(const short8*)&Ps[wq][1][lm][psw];
        #pragma unroll
        for (int jd = 0; jd < 4; ++jd) {
            #pragma unroll
            for (int kk = 0; kk < 2; ++kk) {
                short8 vf = *(const short8*)&Vs[kk][jd * 16 + lm][lk * 8];
                O[jd] = __builtin_amdgcn_mfma_f32_16x16x32_bf16(pf[kk], vf, O[jd], 0, 0, 0);
            }
        }
    }

    float inv[4];
    #pragma unroll
    for (int g = 0; g < 4; ++g) inv[g] = 1.0f / lreg[g];
    #pragma unroll
    for (int jd = 0; jd < 4; ++jd)
        #pragma unroll
        for (int g = 0; g < 4; ++g)
            attn[((size_t)(b * S) + q0 + lk * 4 + g) * E + h * 64 + jd * 16 + lm] =
                f2bf(O[jd][g] * inv[g]);
}

// ---------------------------------------------------------------------------
// Block-local attention (16-key blocks), bf16 in/out. Wave per query, lane = d.
// ---------------------------------------------------------------------------
__global__ __launch_bounds__(256)
void attn_local(const unsigned short* __restrict__ qkv, unsigned short* __restrict__ outp)
{
    const int t = threadIdx.x, lane = t & 63;
    const int gid = blockIdx.x * 4 + (t >> 6);
    const int q = gid & (S - 1);
    const int h = (gid >> 11) & (NH - 1);
    const int b = gid >> 15;

    const unsigned short* base = qkv + (size_t)b * S * E3;
    const float qd = bf2f(base[(size_t)q * E3 + h * DH + lane]) * 0.125f;
    const int j0 = q & ~15;

    float s[16];
    #pragma unroll
    for (int jj = 0; jj < 16; ++jj) {
        const float kd = bf2f(base[(size_t)(j0 + jj) * E3 + E + h * DH + lane]);
        float ps = qd * kd;
        #pragma unroll
        for (int off = 32; off > 0; off >>= 1)
            ps += __shfl_xor(ps, off, 64);
        s[jj] = ps;
    }
    float mx = s[0];
    #pragma unroll
    for (int jj = 1; jj < 16; ++jj) mx = fmaxf(mx, s[jj]);
    float l = 0.f;
    #pragma unroll
    for (int jj = 0; jj < 16; ++jj) { s[jj] = __expf(s[jj] - mx); l += s[jj]; }
    float o = 0.f;
    #pragma unroll
    for (int jj = 0; jj < 16; ++jj) {
        const float vd = bf2f(base[(size_t)(j0 + jj) * E3 + 2 * E + h * DH + lane]);
        o = fmaf(s[jj], vd, o);
    }
    outp[(size_t)(b * S + q) * E + h * DH + lane] = f2bf(o / l);
}

// ---------------------------------------------------------------------------
extern "C" void kernel_launch(void* const* d_in, const int* in_sizes, int n_in,
                              void* d_out, int out_size, void* d_ws, size_t ws_size,
                              hipStream_t stream)
{
    const float* x       = (const float*)d_in[0];
    const float* w_in_g  = (const float*)d_in[1];
    const float* b_in_g  = (const float*)d_in[2];
    const float* w_out_g = (const float*)d_in[3];
    const float* b_out_g = (const float*)d_in[4];
    const float* w_in_l  = (const float*)d_in[5];
    const float* b_in_l  = (const float*)d_in[6];
    const float* w_out_l = (const float*)d_in[7];
    const float* b_out_l = (const float*)d_in[8];
    const float* w_f     = (const float*)d_in[9];
    const float* b_f     = (const float*)d_in[10];
    float* out = (float*)d_out;

    char* p = (char*)d_ws;
    unsigned short* qkv_b   = (unsigned short*)p; p += (size_t)4096 * 3072 * 2;
    unsigned short* xb      = (unsigned short*)p; p += (size_t)4096 * 1024 * 2;
    unsigned short* attn_b  = (unsigned short*)p; p += (size_t)4096 * 1024 * 2;
    unsigned short* proj_b  = (unsigned short*)p; p += (size_t)4096 * 1024 * 2;
    unsigned short* wing_b  = (unsigned short*)p; p += (size_t)3072 * 1024 * 2;
    unsigned short* woutg_b = (unsigned short*)p; p += (size_t)1024 * 1024 * 2;
    unsigned short* winl_b  = (unsigned short*)p; p += (size_t)3072 * 1024 * 2;
    unsigned short* woutl_b = (unsigned short*)p; p += (size_t)1024 * 1024 * 2;
    unsigned short* wf_b    = (unsigned short*)p; p += (size_t)1024 * 2048 * 2;
    unsigned short* vtbuf   = (unsigned short*)p; p += (size_t)Bz * NH * 64 * S * 2;

    dim3 blk(256);
    auto cvt = [&](const float* s, unsigned short* d, int n) {
        cvt_f2b<<<dim3(n / 1024), blk, 0, stream>>>(s, d, n);
    };
    cvt(x,       xb,      4096 * 1024);
    cvt(w_in_g,  wing_b,  3072 * 1024);
    cvt(w_out_g, woutg_b, 1024 * 1024);
    cvt(w_in_l,  winl_b,  3072 * 1024);
    cvt(w_out_l, woutl_b, 1024 * 1024);
    cvt(w_f,     wf_b,    1024 * 2048);

    const int M = Bz * S;   // 4096

    // ---- global branch ----
    gemm_mfma<unsigned short, false><<<dim3(3072 / 128, M / 128), blk, 0, stream>>>(
        xb, wing_b, b_in_g, qkv_b, M, 3072, 1024, 1024);
    vt_transpose<<<dim3(Bz * NH * 32), blk, 0, stream>>>(qkv_b, vtbuf);
    attn_flash<<<dim3(Bz * NH * 32), blk, 0, stream>>>(qkv_b, vtbuf, attn_b);
    gemm_mfma<unsigned short, false><<<dim3(1024 / 128, M / 128), blk, 0, stream>>>(
        attn_b, woutg_b, b_out_g, proj_b, M, 1024, 1024, 1024);
    gemm_mfma<float, false><<<dim3(1024 / 128, M / 128), blk, 0, stream>>>(
        proj_b, wf_b, b_f, out, M, 1024, 1024, 2048);

    // ---- local branch ----
    gemm_mfma<unsigned short, false><<<dim3(3072 / 128, M / 128), blk, 0, stream>>>(
        xb, winl_b, b_in_l, qkv_b, M, 3072, 1024, 1024);
    attn_local<<<dim3(Bz * NH * S / 4), blk, 0, stream>>>(qkv_b, attn_b);
    gemm_mfma<unsigned short, false><<<dim3(1024 / 128, M / 128), blk, 0, stream>>>(
        attn_b, woutl_b, b_out_l, proj_b, M, 1024, 1024, 1024);
    gemm_mfma<float, true><<<dim3(1024 / 128, M / 128), blk, 0, stream>>>(
        proj_b, wf_b + 1024, nullptr, out, M, 1024, 1024, 2048);
}

// Round 5
// 427.424 us; speedup vs baseline: 5.9575x; 1.1805x over previous
//
#include <hip/hip_runtime.h>
#include <hip/hip_bf16.h>
#include <math.h>
#include <stdint.h>

// Problem constants (fixed by the reference).
constexpr int Bz = 2;
constexpr int S  = 2048;
constexpr int E  = 1024;
constexpr int NH = 16;
constexpr int DH = 64;
constexpr int QS = 6144;        // combined qkv row stride: [g q|k|v | l q|k|v]

typedef __attribute__((ext_vector_type(8))) short short8;      // MFMA A/B frag (8 bf16)
typedef __attribute__((ext_vector_type(4))) float f32x4;       // MFMA C/D frag
typedef __attribute__((ext_vector_type(8))) unsigned short bf16x8;
typedef __attribute__((ext_vector_type(4))) unsigned short bf16x4;

__device__ __forceinline__ float bf2f(unsigned short u) {
    union { unsigned int i; float f; } c; c.i = ((unsigned int)u) << 16; return c.f;
}
__device__ __forceinline__ unsigned short f2bf(float f) {   // round-to-nearest-even
    union { float f; unsigned int i; } c; c.f = f;
    unsigned int r = c.i + 0x7fffu + ((c.i >> 16) & 1u);
    return (unsigned short)(r >> 16);
}

#define GLD_LDS(g, l) __builtin_amdgcn_global_load_lds( \
    (const __attribute__((address_space(1))) void*)(g), \
    (__attribute__((address_space(3))) void*)(l), 16, 0, 0)

// ---------------------------------------------------------------------------
// fp32 -> bf16 conversion, 4 elems/thread.
// ---------------------------------------------------------------------------
__global__ __launch_bounds__(256)
void cvt_f2b(const float* __restrict__ src, unsigned short* __restrict__ dst, int n)
{
    const int i = (blockIdx.x * 256 + threadIdx.x) * 4;
    if (i >= n) return;
    float4 v = *(const float4*)(src + i);
    bf16x4 o = { f2bf(v.x), f2bf(v.y), f2bf(v.z), f2bf(v.w) };
    *(bf16x4*)(dst + i) = o;
}

// ---------------------------------------------------------------------------
// bf16 MFMA GEMM (m97 structure, verified R3/R4): C = A @ W^T (+ bias).
// 128x128 tile, BK=32, 4 waves 2x2, 4x4 16x16x32 MFMA per wave.
// lda == K. Optional z-batching: blockIdx.z offsets A/W/C by sAz/sWz/sCz and
// (zbias) selects bias0/bias1 per z; otherwise bias is column-split at nsplit.
// ---------------------------------------------------------------------------
template<typename OutT>
__global__ __launch_bounds__(256)
void gemm_mfma(const unsigned short* __restrict__ A, const unsigned short* __restrict__ W,
               const float* __restrict__ bias0, const float* __restrict__ bias1,
               OutT* __restrict__ C,
               int M, int N, int K, int ldw, int ldc, int nsplit,
               size_t sAz, size_t sWz, size_t sCz, int zbias)
{
    __shared__ __align__(16) short As[128 * 32];
    __shared__ __align__(16) short Bs[128 * 32];
    const int z = blockIdx.z;
    A += z * sAz;  W += z * sWz;  C += z * sCz;
    const float* bia = bias0;
    const float* bib = bias1;
    int ns = nsplit;
    if (zbias) { bia = z ? bias1 : bias0; bib = nullptr; ns = N; }

    const int t = threadIdx.x;
    const int lane = t & 63, wave = t >> 6;
    const int wm = wave & 1, wn = wave >> 1;
    const int m0 = blockIdx.y * 128, n0 = blockIdx.x * 128;
    const int lm = lane & 15, lk = lane >> 4;

    f32x4 acc[4][4] = {};

    const int c1 = t, c2 = t + 256;
    const int r1 = c1 >> 2, kg1 = (c1 & 3) * 8;
    const int r2 = c2 >> 2, kg2 = (c2 & 3) * 8;
    const unsigned short* a1 = A + (size_t)(m0 + r1) * K + kg1;
    const unsigned short* a2 = A + (size_t)(m0 + r2) * K + kg2;
    const unsigned short* w1 = W + (size_t)(n0 + r1) * ldw + kg1;
    const unsigned short* w2 = W + (size_t)(n0 + r2) * ldw + kg2;
    short* ldsA1 = As + (wave * 64) * 8;
    short* ldsA2 = As + (wave * 64 + 256) * 8;
    short* ldsB1 = Bs + (wave * 64) * 8;
    short* ldsB2 = Bs + (wave * 64 + 256) * 8;

    for (int k0 = 0; k0 < K; k0 += 32) {
        __syncthreads();
        GLD_LDS(a1 + k0, ldsA1);
        GLD_LDS(a2 + k0, ldsA2);
        GLD_LDS(w1 + k0, ldsB1);
        GLD_LDS(w2 + k0, ldsB2);
        __syncthreads();

        short8 af[4], bfr[4];
        #pragma unroll
        for (int i = 0; i < 4; ++i)
            af[i] = *(const short8*)&As[(wm * 64 + i * 16 + lm) * 32 + lk * 8];
        #pragma unroll
        for (int j = 0; j < 4; ++j)
            bfr[j] = *(const short8*)&Bs[(wn * 64 + j * 16 + lm) * 32 + lk * 8];
        #pragma unroll
        for (int i = 0; i < 4; ++i)
            #pragma unroll
            for (int j = 0; j < 4; ++j)
                acc[i][j] = __builtin_amdgcn_mfma_f32_16x16x32_bf16(af[i], bfr[j], acc[i][j], 0, 0, 0);
    }

    #pragma unroll
    for (int i = 0; i < 4; ++i) {
        #pragma unroll
        for (int j = 0; j < 4; ++j) {
            const int nn = n0 + wn * 64 + j * 16 + lm;
            const float bv = (nn < ns) ? (bia ? bia[nn] : 0.f)
                                       : (bib ? bib[nn - ns] : 0.f);
            #pragma unroll
            for (int r = 0; r < 4; ++r) {
                const int mm = m0 + wm * 64 + i * 16 + lk * 4 + r;
                const float v = acc[i][j][r] + bv;
                const size_t idx = (size_t)mm * ldc + nn;
                if constexpr (sizeof(OutT) == 2) ((unsigned short*)C)[idx] = f2bf(v);
                else                             C[idx] = v;
            }
        }
    }
}

// ---------------------------------------------------------------------------
// V transpose (global branch): qkv_all V slice [b][s][2048 + h*64 + d]
//   -> vt[(b*NH+h)*64 + d][s]. LDS tile transpose, coalesced both ways.
// ---------------------------------------------------------------------------
__global__ __launch_bounds__(256)
void vt_transpose(const unsigned short* __restrict__ qkv, unsigned short* __restrict__ vt)
{
    __shared__ unsigned short Ts[64][66];
    const int t = threadIdx.x;
    const int bid = blockIdx.x;             // b*512 + h*32 + st
    const int st = bid & 31;
    const int h  = (bid >> 5) & 15;
    const int b  = bid >> 9;
    const int s0 = st * 64;

    #pragma unroll
    for (int r = 0; r < 2; ++r) {
        const int c = r * 256 + t;
        const int key = c >> 3, dg = c & 7;
        bf16x8 v = *(const bf16x8*)(qkv + ((size_t)(b * S) + s0 + key) * QS + 2 * E + h * 64 + dg * 8);
        #pragma unroll
        for (int j = 0; j < 8; ++j) Ts[dg * 8 + j][key] = v[j];
    }
    __syncthreads();
    #pragma unroll
    for (int r = 0; r < 2; ++r) {
        const int c = r * 256 + t;
        const int d = c >> 3, kg = c & 7;
        bf16x8 o;
        #pragma unroll
        for (int j = 0; j < 8; ++j) o[j] = Ts[d][kg * 8 + j];
        *(bf16x8*)(vt + ((size_t)(b * NH + h) * 64 + d) * S + s0 + kg * 8) = o;
    }
}

// ---------------------------------------------------------------------------
// MFMA flash attention v2 — operand-swapped: S^T = K Q^T, O^T = V^T P^T.
// Block = 4 waves = 64 queries of one (b,h); wave owns 16 queries.
// C-layouts put query in the column lanes (lm): softmax m/l/alpha are per-lane
// SCALARS; key-reduction = 15 in-lane ops + shfl_xor(16,32).
// P^T lane holds 4 consecutive keys -> b64 LDS writes (xor-swizzled 8-chunks),
// b128 A/B-frag reads; attn output stores are b64.
// ---------------------------------------------------------------------------
__global__ __launch_bounds__(256, 2)
void attn_flash(const unsigned short* __restrict__ qkv,
                const unsigned short* __restrict__ vt,
                unsigned short* __restrict__ attn)
{
    __shared__ __align__(16) unsigned short Ks[2][64][32];   // [kk][key][d']   8 KB
    __shared__ __align__(16) unsigned short Vs[2][64][32];   // [kk][d][key']   8 KB
    __shared__ __align__(16) unsigned short Pt[4][16][64];   // [wave][query][key_sw] 8 KB

    const int t = threadIdx.x, lane = t & 63, wq = t >> 6;
    const int lm = lane & 15, lk = lane >> 4;
    const int bid = blockIdx.x;              // b*512 + h*32 + qb
    const int qb = bid & 31;
    const int h  = (bid >> 5) & 15;
    const int b  = bid >> 9;
    const int q0 = qb * 64 + wq * 16;        // wave's first query row

    // Q B-frag (query = lm, k = d): pre-scaled by dh^-0.5 = 1/8.
    short8 qf[2];
    {
        const unsigned short* qrow = qkv + ((size_t)(b * S) + q0 + lm) * QS + h * DH;
        #pragma unroll
        for (int kk = 0; kk < 2; ++kk) {
            bf16x8 v = *(const bf16x8*)(qrow + kk * 32 + lk * 8);
            #pragma unroll
            for (int j = 0; j < 8; ++j)
                ((unsigned short*)&qf[kk])[j] = f2bf(bf2f(v[j]) * 0.125f);
        }
    }

    // Staging: thread t stages row0 = t>>2, 8 d/key-elems at (t&3)*8, for r=0,1.
    const int row0 = t >> 2, g0 = (t & 3) * 8;
    const unsigned short* kg[2];
    const unsigned short* vg[2];
    #pragma unroll
    for (int r = 0; r < 2; ++r) {
        kg[r] = qkv + ((size_t)(b * S) + row0) * QS + E + h * 64 + r * 32 + g0;  // [key][d]
        vg[r] = vt + ((size_t)(b * NH + h) * 64 + row0) * S + r * 32 + g0;       // [d][key]
    }
    unsigned short* kl[2] = { &Ks[0][0][0] + (wq * 64) * 8, &Ks[0][0][0] + (256 + wq * 64) * 8 };
    unsigned short* vl[2] = { &Vs[0][0][0] + (wq * 64) * 8, &Vs[0][0][0] + (256 + wq * 64) * 8 };

    f32x4 O[4] = {};                          // O^T tiles: [d rows][query=lm]
    float m = -INFINITY, l = 0.f;             // per-lane scalars (query = lm)
    const int sw = lm & 7;                    // xor-swizzle key-chunk by query

    for (int kt = 0; kt < S / 64; ++kt) {
        __syncthreads();                      // prior tile's K/V reads done
        GLD_LDS(kg[0] + (size_t)kt * 64 * QS, kl[0]);
        GLD_LDS(kg[1] + (size_t)kt * 64 * QS, kl[1]);
        GLD_LDS(vg[0] + kt * 64, vl[0]);
        GLD_LDS(vg[1] + kt * 64, vl[1]);
        __syncthreads();                      // vmcnt drained before use

        // S^T = K Q^T : 8 MFMA. Tile jn rows = keys jn*16 + lk*4 + g, col = lm.
        f32x4 st[4] = {};
        #pragma unroll
        for (int jn = 0; jn < 4; ++jn) {
            #pragma unroll
            for (int kk = 0; kk < 2; ++kk) {
                short8 kf = *(const short8*)&Ks[kk][jn * 16 + lm][lk * 8];
                st[jn] = __builtin_amdgcn_mfma_f32_16x16x32_bf16(kf, qf[kk], st[jn], 0, 0, 0);
            }
        }

        // online softmax over keys (in-lane 16 + shfl_xor 16/32 across lk).
        float vmax = st[0][0];
        #pragma unroll
        for (int jn = 0; jn < 4; ++jn)
            #pragma unroll
            for (int g = 0; g < 4; ++g) vmax = fmaxf(vmax, st[jn][g]);
        vmax = fmaxf(vmax, __shfl_xor(vmax, 16, 64));
        vmax = fmaxf(vmax, __shfl_xor(vmax, 32, 64));
        const float mn = fmaxf(m, vmax);
        const float alpha = __expf(m - mn);
        m = mn;
        float vsum = 0.f;
        #pragma unroll
        for (int jn = 0; jn < 4; ++jn)
            #pragma unroll
            for (int g = 0; g < 4; ++g) {
                const float p = __expf(st[jn][g] - mn);
                st[jn][g] = p;
                vsum += p;
            }
        vsum += __shfl_xor(vsum, 16, 64);
        vsum += __shfl_xor(vsum, 32, 64);
        l = l * alpha + vsum;

        // P^T -> wave-private LDS, b64 writes; chunk c = key>>3 swizzled c^=sw.
        #pragma unroll
        for (int jn = 0; jn < 4; ++jn) {
            const int cc = ((jn * 2 + (lk >> 1)) ^ sw) * 8 + (lk & 1) * 4;
            bf16x4 pk = { f2bf(st[jn][0]), f2bf(st[jn][1]), f2bf(st[jn][2]), f2bf(st[jn][3]) };
            *(bf16x4*)&Pt[wq][lm][cc] = pk;
        }

        // O^T rescale (scalar alpha) then O^T += V^T P^T : 8 MFMA.
        #pragma unroll
        for (int jd = 0; jd < 4; ++jd)
            #pragma unroll
            for (int g = 0; g < 4; ++g) O[jd][g] *= alpha;

        short8 pf[2];
        pf[0] = *(const short8*)&Pt[wq][lm][((lk + 0) ^ sw) * 8];
        pf[1] = *(const short8*)&Pt[wq][lm][((lk + 4) ^ sw) * 8];
        #pragma unroll
        for (int jd = 0; jd < 4; ++jd) {
            #pragma unroll
            for (int kk = 0; kk < 2; ++kk) {
                short8 vf = *(const short8*)&Vs[kk][jd * 16 + lm][lk * 8];
                O[jd] = __builtin_amdgcn_mfma_f32_16x16x32_bf16(vf, pf[kk], O[jd], 0, 0, 0);
            }
        }
    }

    // epilogue: lane owns query lm, d = jd*16 + lk*4 + g -> b64 stores.
    const float inv = 1.0f / l;
    unsigned short* orow = attn + ((size_t)(b * S) + q0 + lm) * E + h * 64;
    #pragma unroll
    for (int jd = 0; jd < 4; ++jd) {
        bf16x4 ov = { f2bf(O[jd][0] * inv), f2bf(O[jd][1] * inv),
                      f2bf(O[jd][2] * inv), f2bf(O[jd][3] * inv) };
        *(bf16x4*)(orow + jd * 16 + lk * 4) = ov;
    }
}

// ---------------------------------------------------------------------------
// Block-local attention (16-key blocks). Wave per query, lane = d.
// Reads the local half of qkv_all (base col 3072), stride QS.
// ---------------------------------------------------------------------------
__global__ __launch_bounds__(256)
void attn_local(const unsigned short* __restrict__ qkvl, unsigned short* __restrict__ outp)
{
    const int t = threadIdx.x, lane = t & 63;
    const int gid = blockIdx.x * 4 + (t >> 6);
    const int q = gid & (S - 1);
    const int h = (gid >> 11) & (NH - 1);
    const int b = gid >> 15;

    const unsigned short* base = qkvl + (size_t)b * S * QS;
    const float qd = bf2f(base[(size_t)q * QS + h * DH + lane]) * 0.125f;
    const int j0 = q & ~15;

    float s[16];
    #pragma unroll
    for (int jj = 0; jj < 16; ++jj) {
        const float kd = bf2f(base[(size_t)(j0 + jj) * QS + E + h * DH + lane]);
        float ps = qd * kd;
        #pragma unroll
        for (int off = 32; off > 0; off >>= 1)
            ps += __shfl_xor(ps, off, 64);
        s[jj] = ps;
    }
    float mx = s[0];
    #pragma unroll
    for (int jj = 1; jj < 16; ++jj) mx = fmaxf(mx, s[jj]);
    float l = 0.f;
    #pragma unroll
    for (int jj = 0; jj < 16; ++jj) { s[jj] = __expf(s[jj] - mx); l += s[jj]; }
    float o = 0.f;
    #pragma unroll
    for (int jj = 0; jj < 16; ++jj) {
        const float vd = bf2f(base[(size_t)(j0 + jj) * QS + 2 * E + h * DH + lane]);
        o = fmaf(s[jj], vd, o);
    }
    outp[(size_t)(b * S + q) * E + h * DH + lane] = f2bf(o / l);
}

// ---------------------------------------------------------------------------
extern "C" void kernel_launch(void* const* d_in, const int* in_sizes, int n_in,
                              void* d_out, int out_size, void* d_ws, size_t ws_size,
                              hipStream_t stream)
{
    const float* x       = (const float*)d_in[0];
    const float* w_in_g  = (const float*)d_in[1];
    const float* b_in_g  = (const float*)d_in[2];
    const float* w_out_g = (const float*)d_in[3];
    const float* b_out_g = (const float*)d_in[4];
    const float* w_in_l  = (const float*)d_in[5];
    const float* b_in_l  = (const float*)d_in[6];
    const float* w_out_l = (const float*)d_in[7];
    const float* b_out_l = (const float*)d_in[8];
    const float* w_f     = (const float*)d_in[9];
    const float* b_f     = (const float*)d_in[10];
    float* out = (float*)d_out;

    const int M = Bz * S;   // 4096
    char* p = (char*)d_ws;
    unsigned short* xb      = (unsigned short*)p; p += (size_t)M * 1024 * 2;        // 8 MB
    unsigned short* qkv_all = (unsigned short*)p; p += (size_t)M * QS * 2;          // 48 MB
    unsigned short* attn_al = (unsigned short*)p; p += (size_t)2 * M * 1024 * 2;    // 16 MB
    unsigned short* proj    = (unsigned short*)p; p += (size_t)M * 2048 * 2;        // 16 MB
    unsigned short* win_all = (unsigned short*)p; p += (size_t)6144 * 1024 * 2;     // 12 MB
    unsigned short* wout_al = (unsigned short*)p; p += (size_t)2 * 1024 * 1024 * 2; //  4 MB
    unsigned short* wf_b    = (unsigned short*)p; p += (size_t)1024 * 2048 * 2;     //  4 MB
    unsigned short* vtbuf   = (unsigned short*)p; p += (size_t)Bz * NH * 64 * S * 2;//  8 MB

    dim3 blk(256);
    auto cvt = [&](const float* s, unsigned short* d, int n) {
        cvt_f2b<<<dim3(n / 1024), blk, 0, stream>>>(s, d, n);
    };
    cvt(x,       xb,                      M * 1024);
    cvt(w_in_g,  win_all,                 3072 * 1024);
    cvt(w_in_l,  win_all + 3072 * 1024,   3072 * 1024);
    cvt(w_out_g, wout_al,                 1024 * 1024);
    cvt(w_out_l, wout_al + 1024 * 1024,   1024 * 1024);
    cvt(w_f,     wf_b,                    1024 * 2048);

    // Combined QKV GEMM: [4096,1024] @ [6144,1024]^T -> qkv_all [4096,6144]
    gemm_mfma<unsigned short><<<dim3(6144 / 128, M / 128, 1), blk, 0, stream>>>(
        xb, win_all, b_in_g, b_in_l, qkv_all,
        M, 6144, 1024, 1024, QS, 3072, 0, 0, 0, 0);

    vt_transpose<<<dim3(Bz * NH * 32), blk, 0, stream>>>(qkv_all, vtbuf);
    attn_flash<<<dim3(Bz * NH * 32), blk, 0, stream>>>(qkv_all, vtbuf, attn_al);
    attn_local<<<dim3(Bz * NH * S / 4), blk, 0, stream>>>(qkv_all + 3072, attn_al + (size_t)M * 1024);

    // Batched out-projections (z=0 global, z=1 local) -> proj [4096,2048]
    gemm_mfma<unsigned short><<<dim3(1024 / 128, M / 128, 2), blk, 0, stream>>>(
        attn_al, wout_al, b_out_g, b_out_l, proj,
        M, 1024, 1024, 1024, 2048, 1024,
        (size_t)M * 1024, (size_t)1024 * 1024, 1024, 1);

    // Fused final GEMM: [4096,2048] @ [1024,2048]^T + b_f -> out (fp32)
    gemm_mfma<float><<<dim3(1024 / 128, M / 128, 1), blk, 0, stream>>>(
        proj, wf_b, b_f, nullptr, out,
        M, 1024, 2048, 2048, 1024, 1024, 0, 0, 0, 0);
}

// Round 6
// 414.244 us; speedup vs baseline: 6.1470x; 1.0318x over previous
//
#include <hip/hip_runtime.h>
#include <hip/hip_bf16.h>
#include <math.h>
#include <stdint.h>

// Problem constants (fixed by the reference).
constexpr int Bz = 2;
constexpr int S  = 2048;
constexpr int E  = 1024;
constexpr int NH = 16;
constexpr int DH = 64;
constexpr int QS = 6144;        // combined qkv row stride: [g q|k|v | l q|k|v]

typedef __attribute__((ext_vector_type(8))) short short8;      // MFMA A/B frag (8 bf16)
typedef __attribute__((ext_vector_type(4))) float f32x4;       // MFMA C/D frag
typedef __attribute__((ext_vector_type(8))) unsigned short bf16x8;
typedef __attribute__((ext_vector_type(4))) unsigned short bf16x4;

__device__ __forceinline__ float bf2f(unsigned short u) {
    union { unsigned int i; float f; } c; c.i = ((unsigned int)u) << 16; return c.f;
}
__device__ __forceinline__ unsigned short f2bf(float f) {   // round-to-nearest-even
    union { float f; unsigned int i; } c; c.f = f;
    unsigned int r = c.i + 0x7fffu + ((c.i >> 16) & 1u);
    return (unsigned short)(r >> 16);
}

// 4x f32 -> packed bf16x4 store (hot path: HW pack if available).
__device__ __forceinline__ void pack4_store(unsigned short* dst,
                                            float a, float b, float c, float d) {
#if __has_builtin(__builtin_amdgcn_cvt_pk_bf16_f32)
    auto p0 = __builtin_amdgcn_cvt_pk_bf16_f32(a, b);
    auto p1 = __builtin_amdgcn_cvt_pk_bf16_f32(c, d);
    union { decltype(p0) v; unsigned int u; } c0, c1;
    c0.v = p0; c1.v = p1;
    uint2 w; w.x = c0.u; w.y = c1.u;
    *(uint2*)dst = w;
#else
    bf16x4 o = { f2bf(a), f2bf(b), f2bf(c), f2bf(d) };
    *(bf16x4*)dst = o;
#endif
}

#define GLD_LDS(g, l) __builtin_amdgcn_global_load_lds( \
    (const __attribute__((address_space(1))) void*)(g), \
    (__attribute__((address_space(3))) void*)(l), 16, 0, 0)

// ---------------------------------------------------------------------------
// Fused fp32 -> bf16 conversion over up to 6 regions (single launch).
// ---------------------------------------------------------------------------
struct CvtJobs {
    const float* src[6];
    unsigned short* dst[6];
    int n[6];               // element counts, multiples of 4
};

__global__ __launch_bounds__(256)
void cvt_all(CvtJobs j)
{
    int i = (blockIdx.x * 256 + threadIdx.x) * 4;
    #pragma unroll
    for (int r = 0; r < 6; ++r) {
        if (i < j.n[r]) {
            float4 v = *(const float4*)(j.src[r] + i);
            bf16x4 o = { f2bf(v.x), f2bf(v.y), f2bf(v.z), f2bf(v.w) };
            *(bf16x4*)(j.dst[r] + i) = o;
            return;
        }
        i -= j.n[r];
    }
}

// ---------------------------------------------------------------------------
// bf16 MFMA GEMM (m97 structure, verified R3-R5): C = A @ W^T (+ bias).
// 128x128 tile, BK=32, 4 waves 2x2, 4x4 16x16x32 MFMA per wave.
// ---------------------------------------------------------------------------
template<typename OutT>
__global__ __launch_bounds__(256)
void gemm_mfma(const unsigned short* __restrict__ A, const unsigned short* __restrict__ W,
               const float* __restrict__ bias0, const float* __restrict__ bias1,
               OutT* __restrict__ C,
               int M, int N, int K, int ldw, int ldc, int nsplit,
               size_t sAz, size_t sWz, size_t sCz, int zbias)
{
    __shared__ __align__(16) short As[128 * 32];
    __shared__ __align__(16) short Bs[128 * 32];
    const int z = blockIdx.z;
    A += z * sAz;  W += z * sWz;  C += z * sCz;
    const float* bia = bias0;
    const float* bib = bias1;
    int ns = nsplit;
    if (zbias) { bia = z ? bias1 : bias0; bib = nullptr; ns = N; }

    const int t = threadIdx.x;
    const int lane = t & 63, wave = t >> 6;
    const int wm = wave & 1, wn = wave >> 1;
    const int m0 = blockIdx.y * 128, n0 = blockIdx.x * 128;
    const int lm = lane & 15, lk = lane >> 4;

    f32x4 acc[4][4] = {};

    const int c1 = t, c2 = t + 256;
    const int r1 = c1 >> 2, kg1 = (c1 & 3) * 8;
    const int r2 = c2 >> 2, kg2 = (c2 & 3) * 8;
    const unsigned short* a1 = A + (size_t)(m0 + r1) * K + kg1;
    const unsigned short* a2 = A + (size_t)(m0 + r2) * K + kg2;
    const unsigned short* w1 = W + (size_t)(n0 + r1) * ldw + kg1;
    const unsigned short* w2 = W + (size_t)(n0 + r2) * ldw + kg2;
    short* ldsA1 = As + (wave * 64) * 8;
    short* ldsA2 = As + (wave * 64 + 256) * 8;
    short* ldsB1 = Bs + (wave * 64) * 8;
    short* ldsB2 = Bs + (wave * 64 + 256) * 8;

    for (int k0 = 0; k0 < K; k0 += 32) {
        __syncthreads();
        GLD_LDS(a1 + k0, ldsA1);
        GLD_LDS(a2 + k0, ldsA2);
        GLD_LDS(w1 + k0, ldsB1);
        GLD_LDS(w2 + k0, ldsB2);
        __syncthreads();

        short8 af[4], bfr[4];
        #pragma unroll
        for (int i = 0; i < 4; ++i)
            af[i] = *(const short8*)&As[(wm * 64 + i * 16 + lm) * 32 + lk * 8];
        #pragma unroll
        for (int j = 0; j < 4; ++j)
            bfr[j] = *(const short8*)&Bs[(wn * 64 + j * 16 + lm) * 32 + lk * 8];
        #pragma unroll
        for (int i = 0; i < 4; ++i)
            #pragma unroll
            for (int j = 0; j < 4; ++j)
                acc[i][j] = __builtin_amdgcn_mfma_f32_16x16x32_bf16(af[i], bfr[j], acc[i][j], 0, 0, 0);
    }

    #pragma unroll
    for (int i = 0; i < 4; ++i) {
        #pragma unroll
        for (int j = 0; j < 4; ++j) {
            const int nn = n0 + wn * 64 + j * 16 + lm;
            const float bv = (nn < ns) ? (bia ? bia[nn] : 0.f)
                                       : (bib ? bib[nn - ns] : 0.f);
            #pragma unroll
            for (int r = 0; r < 4; ++r) {
                const int mm = m0 + wm * 64 + i * 16 + lk * 4 + r;
                const float v = acc[i][j][r] + bv;
                const size_t idx = (size_t)mm * ldc + nn;
                if constexpr (sizeof(OutT) == 2) ((unsigned short*)C)[idx] = f2bf(v);
                else                             C[idx] = v;
            }
        }
    }
}

// ---------------------------------------------------------------------------
// V transpose (global branch): qkv_all V slice [b][s][2048 + h*64 + d]
//   -> vt[(b*NH+h)*64 + d][s].
// ---------------------------------------------------------------------------
__global__ __launch_bounds__(256)
void vt_transpose(const unsigned short* __restrict__ qkv, unsigned short* __restrict__ vt)
{
    __shared__ unsigned short Ts[64][66];
    const int t = threadIdx.x;
    const int bid = blockIdx.x;             // b*512 + h*32 + st
    const int st = bid & 31;
    const int h  = (bid >> 5) & 15;
    const int b  = bid >> 9;
    const int s0 = st * 64;

    #pragma unroll
    for (int r = 0; r < 2; ++r) {
        const int c = r * 256 + t;
        const int key = c >> 3, dg = c & 7;
        bf16x8 v = *(const bf16x8*)(qkv + ((size_t)(b * S) + s0 + key) * QS + 2 * E + h * 64 + dg * 8);
        #pragma unroll
        for (int j = 0; j < 8; ++j) Ts[dg * 8 + j][key] = v[j];
    }
    __syncthreads();
    #pragma unroll
    for (int r = 0; r < 2; ++r) {
        const int c = r * 256 + t;
        const int d = c >> 3, kg = c & 7;
        bf16x8 o;
        #pragma unroll
        for (int j = 0; j < 8; ++j) o[j] = Ts[d][kg * 8 + j];
        *(bf16x8*)(vt + ((size_t)(b * NH + h) * 64 + d) * S + s0 + kg * 8) = o;
    }
}

// ---------------------------------------------------------------------------
// MFMA flash attention v3 — operand-swapped (S^T = K Q^T, O^T = V^T P^T) with
// 2 query groups per wave (32 q/wave, 128 q/block -> grid 512 = 2 blk/CU).
// K/V frag reads amortize over 2x MFMA (LDS-BW was the v2 bottleneck), and
// K/V staging/reads are XOR-swizzled (chunk ^= (row^(row>>2))&3) to turn the
// 8-way b128 read conflicts into free 2-way.
// ---------------------------------------------------------------------------
__global__ __launch_bounds__(256, 2)
void attn_flash(const unsigned short* __restrict__ qkv,
                const unsigned short* __restrict__ vt,
                unsigned short* __restrict__ attn)
{
    __shared__ __align__(16) unsigned short Ks[2][64][32];    // [d-half][key][d-chunks] 8 KB
    __shared__ __align__(16) unsigned short Vs[2][64][32];    // [k-half][d][key-chunks] 8 KB
    __shared__ __align__(16) unsigned short Pt[4][2][16][64]; // [wave][qg][q][key_sw]  16 KB

    const int t = threadIdx.x, lane = t & 63, wq = t >> 6;
    const int lm = lane & 15, lk = lane >> 4;
    const int bid = blockIdx.x;              // b*256 + h*16 + qb
    const int qb = bid & 15;
    const int h  = (bid >> 4) & 15;
    const int b  = bid >> 8;
    const int q0 = qb * 128 + wq * 32;       // wave's first query

    // Q B-frags (query = lm, k = d), pre-scaled by dh^-0.5 = 1/8.
    short8 qf[2][2];
    #pragma unroll
    for (int qg = 0; qg < 2; ++qg) {
        const unsigned short* qrow = qkv + ((size_t)(b * S) + q0 + qg * 16 + lm) * QS + h * DH;
        #pragma unroll
        for (int kk = 0; kk < 2; ++kk) {
            bf16x8 v = *(const bf16x8*)(qrow + kk * 32 + lk * 8);
            #pragma unroll
            for (int j = 0; j < 8; ++j)
                ((unsigned short*)&qf[qg][kk])[j] = f2bf(bf2f(v[j]) * 0.125f);
        }
    }

    // Staging: thread t stages row0 = t>>2; fetches chunk (t&3)^sw0 of each half.
    const int row0 = t >> 2;
    const int sw0 = (row0 ^ (row0 >> 2)) & 3;
    const int g0 = ((t & 3) ^ sw0) * 8;
    const unsigned short* kg[2];
    const unsigned short* vg[2];
    #pragma unroll
    for (int r = 0; r < 2; ++r) {
        kg[r] = qkv + ((size_t)(b * S) + row0) * QS + E + h * 64 + r * 32 + g0;  // [key][d]
        vg[r] = vt + ((size_t)(b * NH + h) * 64 + row0) * S + r * 32 + g0;       // [d][key]
    }
    unsigned short* kl[2] = { &Ks[0][0][0] + (wq * 64) * 8, &Ks[0][0][0] + (256 + wq * 64) * 8 };
    unsigned short* vl[2] = { &Vs[0][0][0] + (wq * 64) * 8, &Vs[0][0][0] + (256 + wq * 64) * 8 };

    f32x4 O[2][4] = {};                       // O^T tiles per qg: [d rows][query=lm]
    float m[2] = { -INFINITY, -INFINITY };
    float l[2] = { 0.f, 0.f };
    const int sw = lm & 7;                    // P chunk swizzle (write side verified 2-way)
    const int fr = (lm ^ (lm >> 2)) & 3;      // K/V frag-read chunk swizzle

    for (int kt = 0; kt < S / 64; ++kt) {
        __syncthreads();                      // prior tile's K/V reads done
        GLD_LDS(kg[0] + (size_t)kt * 64 * QS, kl[0]);
        GLD_LDS(kg[1] + (size_t)kt * 64 * QS, kl[1]);
        GLD_LDS(vg[0] + kt * 64, vl[0]);
        GLD_LDS(vg[1] + kt * 64, vl[1]);
        __syncthreads();                      // vmcnt drained before use

        // S^T = K Q^T : 16 MFMA (K-frags reused across both qg).
        f32x4 st[2][4] = {};
        #pragma unroll
        for (int jn = 0; jn < 4; ++jn) {
            #pragma unroll
            for (int kk = 0; kk < 2; ++kk) {
                short8 kf = *(const short8*)&Ks[kk][jn * 16 + lm][(lk ^ fr) * 8];
                #pragma unroll
                for (int qg = 0; qg < 2; ++qg)
                    st[qg][jn] = __builtin_amdgcn_mfma_f32_16x16x32_bf16(kf, qf[qg][kk], st[qg][jn], 0, 0, 0);
            }
        }

        // online softmax per qg (keys: 16 in-lane + shfl_xor 16/32 across lk).
        float alpha[2];
        #pragma unroll
        for (int qg = 0; qg < 2; ++qg) {
            float vmax = st[qg][0][0];
            #pragma unroll
            for (int jn = 0; jn < 4; ++jn)
                #pragma unroll
                for (int g = 0; g < 4; ++g) vmax = fmaxf(vmax, st[qg][jn][g]);
            vmax = fmaxf(vmax, __shfl_xor(vmax, 16, 64));
            vmax = fmaxf(vmax, __shfl_xor(vmax, 32, 64));
            const float mn = fmaxf(m[qg], vmax);
            alpha[qg] = __expf(m[qg] - mn);
            m[qg] = mn;
            float vsum = 0.f;
            #pragma unroll
            for (int jn = 0; jn < 4; ++jn)
                #pragma unroll
                for (int g = 0; g < 4; ++g) {
                    const float p = __expf(st[qg][jn][g] - mn);
                    st[qg][jn][g] = p;
                    vsum += p;
                }
            vsum += __shfl_xor(vsum, 16, 64);
            vsum += __shfl_xor(vsum, 32, 64);
            l[qg] = l[qg] * alpha[qg] + vsum;
        }

        // P^T -> wave-private LDS (b64, swizzled chunks; 2-way = free).
        #pragma unroll
        for (int qg = 0; qg < 2; ++qg)
            #pragma unroll
            for (int jn = 0; jn < 4; ++jn) {
                const int cc = ((jn * 2 + (lk >> 1)) ^ sw) * 8 + (lk & 1) * 4;
                pack4_store(&Pt[wq][qg][lm][cc],
                            st[qg][jn][0], st[qg][jn][1], st[qg][jn][2], st[qg][jn][3]);
            }

        // O^T rescale then O^T += V^T P^T : 16 MFMA (V-frags reused across qg).
        #pragma unroll
        for (int qg = 0; qg < 2; ++qg)
            #pragma unroll
            for (int jd = 0; jd < 4; ++jd)
                #pragma unroll
                for (int g = 0; g < 4; ++g) O[qg][jd][g] *= alpha[qg];

        short8 pf[2][2];
        #pragma unroll
        for (int qg = 0; qg < 2; ++qg) {
            pf[qg][0] = *(const short8*)&Pt[wq][qg][lm][((lk + 0) ^ sw) * 8];
            pf[qg][1] = *(const short8*)&Pt[wq][qg][lm][((lk + 4) ^ sw) * 8];
        }
        #pragma unroll
        for (int jd = 0; jd < 4; ++jd) {
            #pragma unroll
            for (int kk = 0; kk < 2; ++kk) {
                short8 vf = *(const short8*)&Vs[kk][jd * 16 + lm][(lk ^ fr) * 8];
                #pragma unroll
                for (int qg = 0; qg < 2; ++qg)
                    O[qg][jd] = __builtin_amdgcn_mfma_f32_16x16x32_bf16(vf, pf[qg][kk], O[qg][jd], 0, 0, 0);
            }
        }
    }

    // epilogue: lane owns query lm (per qg), d = jd*16 + lk*4 + g -> b64 stores.
    #pragma unroll
    for (int qg = 0; qg < 2; ++qg) {
        const float inv = 1.0f / l[qg];
        unsigned short* orow = attn + ((size_t)(b * S) + q0 + qg * 16 + lm) * E + h * 64;
        #pragma unroll
        for (int jd = 0; jd < 4; ++jd)
            pack4_store(orow + jd * 16 + lk * 4,
                        O[qg][jd][0] * inv, O[qg][jd][1] * inv,
                        O[qg][jd][2] * inv, O[qg][jd][3] * inv);
    }
}

// ---------------------------------------------------------------------------
// Block-local attention (16-key blocks). Wave per query, lane = d.
// Reads the local half of qkv_all (base col 3072), stride QS.
// ---------------------------------------------------------------------------
__global__ __launch_bounds__(256)
void attn_local(const unsigned short* __restrict__ qkvl, unsigned short* __restrict__ outp)
{
    const int t = threadIdx.x, lane = t & 63;
    const int gid = blockIdx.x * 4 + (t >> 6);
    const int q = gid & (S - 1);
    const int h = (gid >> 11) & (NH - 1);
    const int b = gid >> 15;

    const unsigned short* base = qkvl + (size_t)b * S * QS;
    const float qd = bf2f(base[(size_t)q * QS + h * DH + lane]) * 0.125f;
    const int j0 = q & ~15;

    float s[16];
    #pragma unroll
    for (int jj = 0; jj < 16; ++jj) {
        const float kd = bf2f(base[(size_t)(j0 + jj) * QS + E + h * DH + lane]);
        float ps = qd * kd;
        #pragma unroll
        for (int off = 32; off > 0; off >>= 1)
            ps += __shfl_xor(ps, off, 64);
        s[jj] = ps;
    }
    float mx = s[0];
    #pragma unroll
    for (int jj = 1; jj < 16; ++jj) mx = fmaxf(mx, s[jj]);
    float l = 0.f;
    #pragma unroll
    for (int jj = 0; jj < 16; ++jj) { s[jj] = __expf(s[jj] - mx); l += s[jj]; }
    float o = 0.f;
    #pragma unroll
    for (int jj = 0; jj < 16; ++jj) {
        const float vd = bf2f(base[(size_t)(j0 + jj) * QS + 2 * E + h * DH + lane]);
        o = fmaf(s[jj], vd, o);
    }
    outp[(size_t)(b * S + q) * E + h * DH + lane] = f2bf(o / l);
}

// ---------------------------------------------------------------------------
extern "C" void kernel_launch(void* const* d_in, const int* in_sizes, int n_in,
                              void* d_out, int out_size, void* d_ws, size_t ws_size,
                              hipStream_t stream)
{
    const float* x       = (const float*)d_in[0];
    const float* w_in_g  = (const float*)d_in[1];
    const float* b_in_g  = (const float*)d_in[2];
    const float* w_out_g = (const float*)d_in[3];
    const float* b_out_g = (const float*)d_in[4];
    const float* w_in_l  = (const float*)d_in[5];
    const float* b_in_l  = (const float*)d_in[6];
    const float* w_out_l = (const float*)d_in[7];
    const float* b_out_l = (const float*)d_in[8];
    const float* w_f     = (const float*)d_in[9];
    const float* b_f     = (const float*)d_in[10];
    float* out = (float*)d_out;

    const int M = Bz * S;   // 4096
    char* p = (char*)d_ws;
    unsigned short* xb      = (unsigned short*)p; p += (size_t)M * 1024 * 2;        // 8 MB
    unsigned short* qkv_all = (unsigned short*)p; p += (size_t)M * QS * 2;          // 48 MB
    unsigned short* attn_al = (unsigned short*)p; p += (size_t)2 * M * 1024 * 2;    // 16 MB
    unsigned short* proj    = (unsigned short*)p; p += (size_t)M * 2048 * 2;        // 16 MB
    unsigned short* win_all = (unsigned short*)p; p += (size_t)6144 * 1024 * 2;     // 12 MB
    unsigned short* wout_al = (unsigned short*)p; p += (size_t)2 * 1024 * 1024 * 2; //  4 MB
    unsigned short* wf_b    = (unsigned short*)p; p += (size_t)1024 * 2048 * 2;     //  4 MB
    unsigned short* vtbuf   = (unsigned short*)p; p += (size_t)Bz * NH * 64 * S * 2;//  8 MB

    dim3 blk(256);

    // Single fused conversion launch (fp32 -> bf16, 6 regions, 14.68M elems).
    CvtJobs jobs;
    jobs.src[0] = x;       jobs.dst[0] = xb;                    jobs.n[0] = M * 1024;
    jobs.src[1] = w_in_g;  jobs.dst[1] = win_all;               jobs.n[1] = 3072 * 1024;
    jobs.src[2] = w_in_l;  jobs.dst[2] = win_all + 3072 * 1024; jobs.n[2] = 3072 * 1024;
    jobs.src[3] = w_out_g; jobs.dst[3] = wout_al;               jobs.n[3] = 1024 * 1024;
    jobs.src[4] = w_out_l; jobs.dst[4] = wout_al + 1024 * 1024; jobs.n[4] = 1024 * 1024;
    jobs.src[5] = w_f;     jobs.dst[5] = wf_b;                  jobs.n[5] = 1024 * 2048;
    int total = 0;
    for (int r = 0; r < 6; ++r) total += jobs.n[r];
    cvt_all<<<dim3(total / 1024), blk, 0, stream>>>(jobs);

    // Combined QKV GEMM: [4096,1024] @ [6144,1024]^T -> qkv_all [4096,6144]
    gemm_mfma<unsigned short><<<dim3(6144 / 128, M / 128, 1), blk, 0, stream>>>(
        xb, win_all, b_in_g, b_in_l, qkv_all,
        M, 6144, 1024, 1024, QS, 3072, 0, 0, 0, 0);

    vt_transpose<<<dim3(Bz * NH * 32), blk, 0, stream>>>(qkv_all, vtbuf);
    attn_flash<<<dim3(Bz * NH * (S / 128)), blk, 0, stream>>>(qkv_all, vtbuf, attn_al);
    attn_local<<<dim3(Bz * NH * S / 4), blk, 0, stream>>>(qkv_all + 3072, attn_al + (size_t)M * 1024);

    // Batched out-projections (z=0 global, z=1 local) -> proj [4096,2048]
    gemm_mfma<unsigned short><<<dim3(1024 / 128, M / 128, 2), blk, 0, stream>>>(
        attn_al, wout_al, b_out_g, b_out_l, proj,
        M, 1024, 1024, 1024, 2048, 1024,
        (size_t)M * 1024, (size_t)1024 * 1024, 1024, 1);

    // Fused final GEMM: [4096,2048] @ [1024,2048]^T + b_f -> out (fp32)
    gemm_mfma<float><<<dim3(1024 / 128, M / 128, 1), blk, 0, stream>>>(
        proj, wf_b, b_f, nullptr, out,
        M, 1024, 2048, 2048, 1024, 1024, 0, 0, 0, 0);
}

// Round 7
// 412.645 us; speedup vs baseline: 6.1708x; 1.0039x over previous
//
#include <hip/hip_runtime.h>
#include <hip/hip_bf16.h>
#include <math.h>
#include <stdint.h>

// Problem constants (fixed by the reference).
constexpr int Bz = 2;
constexpr int S  = 2048;
constexpr int E  = 1024;
constexpr int NH = 16;
constexpr int DH = 64;
constexpr int QS = 6144;        // combined qkv row stride: [g q|k|v | l q|k|v]

typedef __attribute__((ext_vector_type(8))) short short8;      // MFMA A/B frag (8 bf16)
typedef __attribute__((ext_vector_type(4))) float f32x4;       // MFMA C/D frag
typedef __attribute__((ext_vector_type(8))) unsigned short bf16x8;
typedef __attribute__((ext_vector_type(4))) unsigned short bf16x4;

__device__ __forceinline__ float bf2f(unsigned short u) {
    union { unsigned int i; float f; } c; c.i = ((unsigned int)u) << 16; return c.f;
}
__device__ __forceinline__ unsigned short f2bf(float f) {   // round-to-nearest-even
    union { float f; unsigned int i; } c; c.f = f;
    unsigned int r = c.i + 0x7fffu + ((c.i >> 16) & 1u);
    return (unsigned short)(r >> 16);
}

// 4x f32 -> packed bf16x4 store (hot path: HW pack if available).
__device__ __forceinline__ void pack4_store(unsigned short* dst,
                                            float a, float b, float c, float d) {
#if __has_builtin(__builtin_amdgcn_cvt_pk_bf16_f32)
    auto p0 = __builtin_amdgcn_cvt_pk_bf16_f32(a, b);
    auto p1 = __builtin_amdgcn_cvt_pk_bf16_f32(c, d);
    union { decltype(p0) v; unsigned int u; } c0, c1;
    c0.v = p0; c1.v = p1;
    uint2 w; w.x = c0.u; w.y = c1.u;
    *(uint2*)dst = w;
#else
    bf16x4 o = { f2bf(a), f2bf(b), f2bf(c), f2bf(d) };
    *(bf16x4*)dst = o;
#endif
}

#define GLD_LDS(g, l) __builtin_amdgcn_global_load_lds( \
    (const __attribute__((address_space(1))) void*)(g), \
    (__attribute__((address_space(3))) void*)(l), 16, 0, 0)

// ---------------------------------------------------------------------------
// Fused fp32 -> bf16 conversion over up to 6 regions (single launch).
// ---------------------------------------------------------------------------
struct CvtJobs {
    const float* src[6];
    unsigned short* dst[6];
    int n[6];               // element counts, multiples of 4 (0 = unused)
};

__global__ __launch_bounds__(256)
void cvt_all(CvtJobs j)
{
    int i = (blockIdx.x * 256 + threadIdx.x) * 4;
    #pragma unroll
    for (int r = 0; r < 6; ++r) {
        if (i < j.n[r]) {
            float4 v = *(const float4*)(j.src[r] + i);
            bf16x4 o = { f2bf(v.x), f2bf(v.y), f2bf(v.z), f2bf(v.w) };
            *(bf16x4*)(j.dst[r] + i) = o;
            return;
        }
        i -= j.n[r];
    }
}

// ---------------------------------------------------------------------------
// Transpose-convert: two 1024x1024 fp32 mats -> bf16 transposed.
// dstT[j][i] = src[i][j]. 64x64 LDS tiles, coalesced both sides.
// grid = 2 * 16 * 16 = 512 blocks.
// ---------------------------------------------------------------------------
__global__ __launch_bounds__(256)
void trcvt_wout(const float* __restrict__ s0, const float* __restrict__ s1,
                unsigned short* __restrict__ d0, unsigned short* __restrict__ d1)
{
    __shared__ unsigned short T[64][72];
    const int t = threadIdx.x;
    const int bid = blockIdx.x;
    const int tj = bid & 15, ti = (bid >> 4) & 15, mat = bid >> 8;
    const float* src = mat ? s1 : s0;
    unsigned short* dst = mat ? d1 : d0;

    #pragma unroll
    for (int r = 0; r < 4; ++r) {
        const int c = r * 256 + t;
        const int row = c >> 4, col4 = (c & 15) * 4;
        float4 v = *(const float4*)(src + (size_t)(ti * 64 + row) * 1024 + tj * 64 + col4);
        T[col4 + 0][row] = f2bf(v.x);
        T[col4 + 1][row] = f2bf(v.y);
        T[col4 + 2][row] = f2bf(v.z);
        T[col4 + 3][row] = f2bf(v.w);
    }
    __syncthreads();
    #pragma unroll
    for (int r = 0; r < 2; ++r) {
        const int c = r * 256 + t;
        const int jrow = c >> 3, ig = (c & 7) * 8;
        bf16x8 o;
        #pragma unroll
        for (int k = 0; k < 8; ++k) o[k] = T[jrow][ig + k];
        *(bf16x8*)(dst + (size_t)(tj * 64 + jrow) * 1024 + ti * 64 + ig) = o;
    }
}

// ---------------------------------------------------------------------------
// Combined bias: cb[n] = b_f[n] + sum_j wf[n,j]*bog[j] + sum_j wf[n,1024+j]*bol[j].
// One wave per n (fp32 math, coalesced wf reads).
// ---------------------------------------------------------------------------
__global__ __launch_bounds__(256)
void bias_comb(const float* __restrict__ wf, const float* __restrict__ bf,
               const float* __restrict__ bog, const float* __restrict__ bol,
               float* __restrict__ cb)
{
    const int t = threadIdx.x, lane = t & 63;
    const int n = blockIdx.x * 4 + (t >> 6);
    const float* row = wf + (size_t)n * 2048;
    float s = 0.f;
    #pragma unroll
    for (int i = 0; i < 16; ++i) s = fmaf(row[i * 64 + lane], bog[i * 64 + lane], s);
    #pragma unroll
    for (int i = 16; i < 32; ++i) s = fmaf(row[i * 64 + lane], bol[i * 64 + lane - 1024], s);
    #pragma unroll
    for (int off = 32; off > 0; off >>= 1) s += __shfl_xor(s, off, 64);
    if (lane == 0) cb[n] = bf[n] + s;
}

// ---------------------------------------------------------------------------
// bf16 MFMA GEMM (m97 structure, verified R3-R6): C = A @ W^T (+ bias).
// 128x128 tile, BK=32, 4 waves 2x2, 4x4 16x16x32 MFMA per wave.
// lda: A row stride. z-batching via sAz/sWz/sCz element offsets.
// ---------------------------------------------------------------------------
template<typename OutT>
__global__ __launch_bounds__(256)
void gemm_mfma(const unsigned short* __restrict__ A, const unsigned short* __restrict__ W,
               const float* __restrict__ bias0, const float* __restrict__ bias1,
               OutT* __restrict__ C,
               int M, int N, int K, int lda, int ldw, int ldc, int nsplit,
               size_t sAz, size_t sWz, size_t sCz, int zbias)
{
    __shared__ __align__(16) short As[128 * 32];
    __shared__ __align__(16) short Bs[128 * 32];
    const int z = blockIdx.z;
    A += z * sAz;  W += z * sWz;  C += z * sCz;
    const float* bia = bias0;
    const float* bib = bias1;
    int ns = nsplit;
    if (zbias) { bia = z ? bias1 : bias0; bib = nullptr; ns = N; }

    const int t = threadIdx.x;
    const int lane = t & 63, wave = t >> 6;
    const int wm = wave & 1, wn = wave >> 1;
    const int m0 = blockIdx.y * 128, n0 = blockIdx.x * 128;
    const int lm = lane & 15, lk = lane >> 4;

    f32x4 acc[4][4] = {};

    const int c1 = t, c2 = t + 256;
    const int r1 = c1 >> 2, kg1 = (c1 & 3) * 8;
    const int r2 = c2 >> 2, kg2 = (c2 & 3) * 8;
    const unsigned short* a1 = A + (size_t)(m0 + r1) * lda + kg1;
    const unsigned short* a2 = A + (size_t)(m0 + r2) * lda + kg2;
    const unsigned short* w1 = W + (size_t)(n0 + r1) * ldw + kg1;
    const unsigned short* w2 = W + (size_t)(n0 + r2) * ldw + kg2;
    short* ldsA1 = As + (wave * 64) * 8;
    short* ldsA2 = As + (wave * 64 + 256) * 8;
    short* ldsB1 = Bs + (wave * 64) * 8;
    short* ldsB2 = Bs + (wave * 64 + 256) * 8;

    for (int k0 = 0; k0 < K; k0 += 32) {
        __syncthreads();
        GLD_LDS(a1 + k0, ldsA1);
        GLD_LDS(a2 + k0, ldsA2);
        GLD_LDS(w1 + k0, ldsB1);
        GLD_LDS(w2 + k0, ldsB2);
        __syncthreads();

        short8 af[4], bfr[4];
        #pragma unroll
        for (int i = 0; i < 4; ++i)
            af[i] = *(const short8*)&As[(wm * 64 + i * 16 + lm) * 32 + lk * 8];
        #pragma unroll
        for (int j = 0; j < 4; ++j)
            bfr[j] = *(const short8*)&Bs[(wn * 64 + j * 16 + lm) * 32 + lk * 8];
        #pragma unroll
        for (int i = 0; i < 4; ++i)
            #pragma unroll
            for (int j = 0; j < 4; ++j)
                acc[i][j] = __builtin_amdgcn_mfma_f32_16x16x32_bf16(af[i], bfr[j], acc[i][j], 0, 0, 0);
    }

    #pragma unroll
    for (int i = 0; i < 4; ++i) {
        #pragma unroll
        for (int j = 0; j < 4; ++j) {
            const int nn = n0 + wn * 64 + j * 16 + lm;
            const float bv = (nn < ns) ? (bia ? bia[nn] : 0.f)
                                       : (bib ? bib[nn - ns] : 0.f);
            #pragma unroll
            for (int r = 0; r < 4; ++r) {
                const int mm = m0 + wm * 64 + i * 16 + lk * 4 + r;
                const float v = acc[i][j][r] + bv;
                const size_t idx = (size_t)mm * ldc + nn;
                if constexpr (sizeof(OutT) == 2) ((unsigned short*)C)[idx] = f2bf(v);
                else                             C[idx] = v;
            }
        }
    }
}

// ---------------------------------------------------------------------------
// V transpose (global branch): qkv_all V slice [b][s][2048 + h*64 + d]
//   -> vt[(b*NH+h)*64 + d][s].
// ---------------------------------------------------------------------------
__global__ __launch_bounds__(256)
void vt_transpose(const unsigned short* __restrict__ qkv, unsigned short* __restrict__ vt)
{
    __shared__ unsigned short Ts[64][66];
    const int t = threadIdx.x;
    const int bid = blockIdx.x;             // b*512 + h*32 + st
    const int st = bid & 31;
    const int h  = (bid >> 5) & 15;
    const int b  = bid >> 9;
    const int s0 = st * 64;

    #pragma unroll
    for (int r = 0; r < 2; ++r) {
        const int c = r * 256 + t;
        const int key = c >> 3, dg = c & 7;
        bf16x8 v = *(const bf16x8*)(qkv + ((size_t)(b * S) + s0 + key) * QS + 2 * E + h * 64 + dg * 8);
        #pragma unroll
        for (int j = 0; j < 8; ++j) Ts[dg * 8 + j][key] = v[j];
    }
    __syncthreads();
    #pragma unroll
    for (int r = 0; r < 2; ++r) {
        const int c = r * 256 + t;
        const int d = c >> 3, kg = c & 7;
        bf16x8 o;
        #pragma unroll
        for (int j = 0; j < 8; ++j) o[j] = Ts[d][kg * 8 + j];
        *(bf16x8*)(vt + ((size_t)(b * NH + h) * 64 + d) * S + s0 + kg * 8) = o;
    }
}

// ---------------------------------------------------------------------------
// MFMA flash attention v3 (verified R6): operand-swapped, 2 q-groups/wave.
// Writes into attn_cat [4096][2048], global half (cols h*64, row stride 2048).
// ---------------------------------------------------------------------------
__global__ __launch_bounds__(256, 2)
void attn_flash(const unsigned short* __restrict__ qkv,
                const unsigned short* __restrict__ vt,
                unsigned short* __restrict__ attn)
{
    __shared__ __align__(16) unsigned short Ks[2][64][32];    // 8 KB
    __shared__ __align__(16) unsigned short Vs[2][64][32];    // 8 KB
    __shared__ __align__(16) unsigned short Pt[4][2][16][64]; // 16 KB

    const int t = threadIdx.x, lane = t & 63, wq = t >> 6;
    const int lm = lane & 15, lk = lane >> 4;
    const int bid = blockIdx.x;              // b*256 + h*16 + qb
    const int qb = bid & 15;
    const int h  = (bid >> 4) & 15;
    const int b  = bid >> 8;
    const int q0 = qb * 128 + wq * 32;       // wave's first query

    short8 qf[2][2];
    #pragma unroll
    for (int qg = 0; qg < 2; ++qg) {
        const unsigned short* qrow = qkv + ((size_t)(b * S) + q0 + qg * 16 + lm) * QS + h * DH;
        #pragma unroll
        for (int kk = 0; kk < 2; ++kk) {
            bf16x8 v = *(const bf16x8*)(qrow + kk * 32 + lk * 8);
            #pragma unroll
            for (int j = 0; j < 8; ++j)
                ((unsigned short*)&qf[qg][kk])[j] = f2bf(bf2f(v[j]) * 0.125f);
        }
    }

    const int row0 = t >> 2;
    const int sw0 = (row0 ^ (row0 >> 2)) & 3;
    const int g0 = ((t & 3) ^ sw0) * 8;
    const unsigned short* kg[2];
    const unsigned short* vg[2];
    #pragma unroll
    for (int r = 0; r < 2; ++r) {
        kg[r] = qkv + ((size_t)(b * S) + row0) * QS + E + h * 64 + r * 32 + g0;
        vg[r] = vt + ((size_t)(b * NH + h) * 64 + row0) * S + r * 32 + g0;
    }
    unsigned short* kl[2] = { &Ks[0][0][0] + (wq * 64) * 8, &Ks[0][0][0] + (256 + wq * 64) * 8 };
    unsigned short* vl[2] = { &Vs[0][0][0] + (wq * 64) * 8, &Vs[0][0][0] + (256 + wq * 64) * 8 };

    f32x4 O[2][4] = {};
    float m[2] = { -INFINITY, -INFINITY };
    float l[2] = { 0.f, 0.f };
    const int sw = lm & 7;
    const int fr = (lm ^ (lm >> 2)) & 3;

    for (int kt = 0; kt < S / 64; ++kt) {
        __syncthreads();
        GLD_LDS(kg[0] + (size_t)kt * 64 * QS, kl[0]);
        GLD_LDS(kg[1] + (size_t)kt * 64 * QS, kl[1]);
        GLD_LDS(vg[0] + kt * 64, vl[0]);
        GLD_LDS(vg[1] + kt * 64, vl[1]);
        __syncthreads();

        f32x4 st[2][4] = {};
        #pragma unroll
        for (int jn = 0; jn < 4; ++jn) {
            #pragma unroll
            for (int kk = 0; kk < 2; ++kk) {
                short8 kf = *(const short8*)&Ks[kk][jn * 16 + lm][(lk ^ fr) * 8];
                #pragma unroll
                for (int qg = 0; qg < 2; ++qg)
                    st[qg][jn] = __builtin_amdgcn_mfma_f32_16x16x32_bf16(kf, qf[qg][kk], st[qg][jn], 0, 0, 0);
            }
        }

        float alpha[2];
        #pragma unroll
        for (int qg = 0; qg < 2; ++qg) {
            float vmax = st[qg][0][0];
            #pragma unroll
            for (int jn = 0; jn < 4; ++jn)
                #pragma unroll
                for (int g = 0; g < 4; ++g) vmax = fmaxf(vmax, st[qg][jn][g]);
            vmax = fmaxf(vmax, __shfl_xor(vmax, 16, 64));
            vmax = fmaxf(vmax, __shfl_xor(vmax, 32, 64));
            const float mn = fmaxf(m[qg], vmax);
            alpha[qg] = __expf(m[qg] - mn);
            m[qg] = mn;
            float vsum = 0.f;
            #pragma unroll
            for (int jn = 0; jn < 4; ++jn)
                #pragma unroll
                for (int g = 0; g < 4; ++g) {
                    const float p = __expf(st[qg][jn][g] - mn);
                    st[qg][jn][g] = p;
                    vsum += p;
                }
            vsum += __shfl_xor(vsum, 16, 64);
            vsum += __shfl_xor(vsum, 32, 64);
            l[qg] = l[qg] * alpha[qg] + vsum;
        }

        #pragma unroll
        for (int qg = 0; qg < 2; ++qg)
            #pragma unroll
            for (int jn = 0; jn < 4; ++jn) {
                const int cc = ((jn * 2 + (lk >> 1)) ^ sw) * 8 + (lk & 1) * 4;
                pack4_store(&Pt[wq][qg][lm][cc],
                            st[qg][jn][0], st[qg][jn][1], st[qg][jn][2], st[qg][jn][3]);
            }

        #pragma unroll
        for (int qg = 0; qg < 2; ++qg)
            #pragma unroll
            for (int jd = 0; jd < 4; ++jd)
                #pragma unroll
                for (int g = 0; g < 4; ++g) O[qg][jd][g] *= alpha[qg];

        short8 pf[2][2];
        #pragma unroll
        for (int qg = 0; qg < 2; ++qg) {
            pf[qg][0] = *(const short8*)&Pt[wq][qg][lm][((lk + 0) ^ sw) * 8];
            pf[qg][1] = *(const short8*)&Pt[wq][qg][lm][((lk + 4) ^ sw) * 8];
        }
        #pragma unroll
        for (int jd = 0; jd < 4; ++jd) {
            #pragma unroll
            for (int kk = 0; kk < 2; ++kk) {
                short8 vf = *(const short8*)&Vs[kk][jd * 16 + lm][(lk ^ fr) * 8];
                #pragma unroll
                for (int qg = 0; qg < 2; ++qg)
                    O[qg][jd] = __builtin_amdgcn_mfma_f32_16x16x32_bf16(vf, pf[qg][kk], O[qg][jd], 0, 0, 0);
            }
        }
    }

    #pragma unroll
    for (int qg = 0; qg < 2; ++qg) {
        const float inv = 1.0f / l[qg];
        unsigned short* orow = attn + ((size_t)(b * S) + q0 + qg * 16 + lm) * 2048 + h * 64;
        #pragma unroll
        for (int jd = 0; jd < 4; ++jd)
            pack4_store(orow + jd * 16 + lk * 4,
                        O[qg][jd][0] * inv, O[qg][jd][1] * inv,
                        O[qg][jd][2] * inv, O[qg][jd][3] * inv);
    }
}

// ---------------------------------------------------------------------------
// Block-local attention (16-key blocks). Wave per query, lane = d.
// Writes into attn_cat local half (cols 1024 + h*64, row stride 2048).
// ---------------------------------------------------------------------------
__global__ __launch_bounds__(256)
void attn_local(const unsigned short* __restrict__ qkvl, unsigned short* __restrict__ outp)
{
    const int t = threadIdx.x, lane = t & 63;
    const int gid = blockIdx.x * 4 + (t >> 6);
    const int q = gid & (S - 1);
    const int h = (gid >> 11) & (NH - 1);
    const int b = gid >> 15;

    const unsigned short* base = qkvl + (size_t)b * S * QS;
    const float qd = bf2f(base[(size_t)q * QS + h * DH + lane]) * 0.125f;
    const int j0 = q & ~15;

    float s[16];
    #pragma unroll
    for (int jj = 0; jj < 16; ++jj) {
        const float kd = bf2f(base[(size_t)(j0 + jj) * QS + E + h * DH + lane]);
        float ps = qd * kd;
        #pragma unroll
        for (int off = 32; off > 0; off >>= 1)
            ps += __shfl_xor(ps, off, 64);
        s[jj] = ps;
    }
    float mx = s[0];
    #pragma unroll
    for (int jj = 1; jj < 16; ++jj) mx = fmaxf(mx, s[jj]);
    float l = 0.f;
    #pragma unroll
    for (int jj = 0; jj < 16; ++jj) { s[jj] = __expf(s[jj] - mx); l += s[jj]; }
    float o = 0.f;
    #pragma unroll
    for (int jj = 0; jj < 16; ++jj) {
        const float vd = bf2f(base[(size_t)(j0 + jj) * QS + 2 * E + h * DH + lane]);
        o = fmaf(s[jj], vd, o);
    }
    outp[(size_t)(b * S + q) * 2048 + 1024 + h * DH + lane] = f2bf(o / l);
}

// ---------------------------------------------------------------------------
extern "C" void kernel_launch(void* const* d_in, const int* in_sizes, int n_in,
                              void* d_out, int out_size, void* d_ws, size_t ws_size,
                              hipStream_t stream)
{
    const float* x       = (const float*)d_in[0];
    const float* w_in_g  = (const float*)d_in[1];
    const float* b_in_g  = (const float*)d_in[2];
    const float* w_out_g = (const float*)d_in[3];
    const float* b_out_g = (const float*)d_in[4];
    const float* w_in_l  = (const float*)d_in[5];
    const float* b_in_l  = (const float*)d_in[6];
    const float* w_out_l = (const float*)d_in[7];
    const float* b_out_l = (const float*)d_in[8];
    const float* w_f     = (const float*)d_in[9];
    const float* b_f     = (const float*)d_in[10];
    float* out = (float*)d_out;

    const int M = Bz * S;   // 4096
    char* p = (char*)d_ws;
    unsigned short* xb       = (unsigned short*)p; p += (size_t)M * 1024 * 2;        //  8 MB
    unsigned short* qkv_all  = (unsigned short*)p; p += (size_t)M * QS * 2;          // 48 MB
    unsigned short* attn_cat = (unsigned short*)p; p += (size_t)M * 2048 * 2;        // 16 MB
    unsigned short* win_all  = (unsigned short*)p; p += (size_t)6144 * 1024 * 2;     // 12 MB
    unsigned short* wf_b     = (unsigned short*)p; p += (size_t)1024 * 2048 * 2;     //  4 MB
    unsigned short* woutT    = (unsigned short*)p; p += (size_t)2 * 1024 * 1024 * 2; //  4 MB
    unsigned short* wcomb    = (unsigned short*)p; p += (size_t)1024 * 2048 * 2;     //  4 MB
    unsigned short* vtbuf    = (unsigned short*)p; p += (size_t)Bz * NH * 64 * S * 2;//  8 MB
    float*          cb       = (float*)p;          p += 1024 * 4;

    dim3 blk(256);

    // fp32 -> bf16 (x, w_in_g, w_in_l, w_f) in one launch.
    CvtJobs jobs;
    jobs.src[0] = x;      jobs.dst[0] = xb;                    jobs.n[0] = M * 1024;
    jobs.src[1] = w_in_g; jobs.dst[1] = win_all;               jobs.n[1] = 3072 * 1024;
    jobs.src[2] = w_in_l; jobs.dst[2] = win_all + 3072 * 1024; jobs.n[2] = 3072 * 1024;
    jobs.src[3] = w_f;    jobs.dst[3] = wf_b;                  jobs.n[3] = 1024 * 2048;
    jobs.src[4] = x;      jobs.dst[4] = xb;                    jobs.n[4] = 0;
    jobs.src[5] = x;      jobs.dst[5] = xb;                    jobs.n[5] = 0;
    int total = 0;
    for (int r = 0; r < 6; ++r) total += jobs.n[r];
    cvt_all<<<dim3(total / 1024), blk, 0, stream>>>(jobs);

    // w_out_g/l -> bf16 transposed.
    trcvt_wout<<<dim3(512), blk, 0, stream>>>(w_out_g, w_out_l, woutT, woutT + 1024 * 1024);

    // Wcomb_z[n,k] = sum_j wf[n, z*1024+j] * w_out_z[j,k]  -> wcomb [1024][2048] bf16.
    gemm_mfma<unsigned short><<<dim3(8, 8, 2), blk, 0, stream>>>(
        wf_b, woutT, nullptr, nullptr, wcomb,
        1024, 1024, 1024, 2048, 1024, 2048, 1024,
        1024, (size_t)1024 * 1024, 1024, 0);

    // cb[n] = b_f[n] + wf[n,:1024]@b_out_g + wf[n,1024:]@b_out_l (fp32).
    bias_comb<<<dim3(256), blk, 0, stream>>>(w_f, b_f, b_out_g, b_out_l, cb);

    // Combined QKV GEMM: [4096,1024] @ [6144,1024]^T -> qkv_all [4096,6144]
    gemm_mfma<unsigned short><<<dim3(6144 / 128, M / 128, 1), blk, 0, stream>>>(
        xb, win_all, b_in_g, b_in_l, qkv_all,
        M, 6144, 1024, 1024, 1024, QS, 3072, 0, 0, 0, 0);

    vt_transpose<<<dim3(Bz * NH * 32), blk, 0, stream>>>(qkv_all, vtbuf);
    attn_flash<<<dim3(Bz * NH * (S / 128)), blk, 0, stream>>>(qkv_all, vtbuf, attn_cat);
    attn_local<<<dim3(Bz * NH * S / 4), blk, 0, stream>>>(qkv_all + 3072, attn_cat);

    // Fused tail: out = attn_cat [4096,2048] @ wcomb[1024,2048]^T + cb (fp32 out).
    gemm_mfma<float><<<dim3(1024 / 128, M / 128, 1), blk, 0, stream>>>(
        attn_cat, wcomb, cb, nullptr, out,
        M, 1024, 2048, 2048, 2048, 1024, 1024, 0, 0, 0, 0);
}

// Round 8
// 379.508 us; speedup vs baseline: 6.7096x; 1.0873x over previous
//
#include <hip/hip_runtime.h>
#include <hip/hip_bf16.h>
#include <math.h>
#include <stdint.h>

// Problem constants (fixed by the reference).
constexpr int Bz = 2;
constexpr int S  = 2048;
constexpr int E  = 1024;
constexpr int NH = 16;
constexpr int DH = 64;
constexpr int QS = 6144;        // combined qkv row stride: [g q|k|v | l q|k|v]

typedef __attribute__((ext_vector_type(8))) short short8;      // MFMA A/B frag (8 bf16)
typedef __attribute__((ext_vector_type(4))) float f32x4;       // MFMA C/D frag
typedef __attribute__((ext_vector_type(8))) unsigned short bf16x8;
typedef __attribute__((ext_vector_type(4))) unsigned short bf16x4;

__device__ __forceinline__ float bf2f(unsigned short u) {
    union { unsigned int i; float f; } c; c.i = ((unsigned int)u) << 16; return c.f;
}
__device__ __forceinline__ unsigned short f2bf(float f) {   // round-to-nearest-even
    union { float f; unsigned int i; } c; c.f = f;
    unsigned int r = c.i + 0x7fffu + ((c.i >> 16) & 1u);
    return (unsigned short)(r >> 16);
}

// 4x f32 -> packed bf16x4 store (hot path: HW pack if available).
__device__ __forceinline__ void pack4_store(unsigned short* dst,
                                            float a, float b, float c, float d) {
#if __has_builtin(__builtin_amdgcn_cvt_pk_bf16_f32)
    auto p0 = __builtin_amdgcn_cvt_pk_bf16_f32(a, b);
    auto p1 = __builtin_amdgcn_cvt_pk_bf16_f32(c, d);
    union { decltype(p0) v; unsigned int u; } c0, c1;
    c0.v = p0; c1.v = p1;
    uint2 w; w.x = c0.u; w.y = c1.u;
    *(uint2*)dst = w;
#else
    bf16x4 o = { f2bf(a), f2bf(b), f2bf(c), f2bf(d) };
    *(bf16x4*)dst = o;
#endif
}

#define GLD_LDS(g, l) __builtin_amdgcn_global_load_lds( \
    (const __attribute__((address_space(1))) void*)(g), \
    (__attribute__((address_space(3))) void*)(l), 16, 0, 0)

// ---------------------------------------------------------------------------
// prep_all — one launch for all preprocessing:
//   blocks [0, 12288)      : fp32->bf16 cvt of {x, w_in_g, w_in_l, w_f}
//   blocks [12288, 12800)  : transpose-convert w_out_g/l -> bf16 woutT
//   blocks [12800, 13056)  : cb[n] = b_f + wf[:, :1024]@bog + wf[:, 1024:]@bol
// ---------------------------------------------------------------------------
struct PrepArgs {
    const float* csrc[4]; unsigned short* cdst[4]; int cn[4];
    const float* wog; const float* wol;
    unsigned short* wogT; unsigned short* wolT;
    const float* wf; const float* bf; const float* bog; const float* bol;
    float* cb;
};

__global__ __launch_bounds__(256)
void prep_all(PrepArgs a)
{
    __shared__ unsigned short T[64][72];
    const int bid = blockIdx.x, t = threadIdx.x;

    if (bid < 12288) {                      // ---- cvt path
        int i = (bid * 256 + t) * 4;
        #pragma unroll
        for (int r = 0; r < 4; ++r) {
            if (i < a.cn[r]) {
                float4 v = *(const float4*)(a.csrc[r] + i);
                bf16x4 o = { f2bf(v.x), f2bf(v.y), f2bf(v.z), f2bf(v.w) };
                *(bf16x4*)(a.cdst[r] + i) = o;
                return;
            }
            i -= a.cn[r];
        }
        return;
    }
    if (bid < 12800) {                      // ---- transpose-convert path
        const int id = bid - 12288;
        const int tj = id & 15, ti = (id >> 4) & 15, mat = id >> 8;
        const float* src = mat ? a.wol : a.wog;
        unsigned short* dst = mat ? a.wolT : a.wogT;
        #pragma unroll
        for (int r = 0; r < 4; ++r) {
            const int c = r * 256 + t;
            const int row = c >> 4, col4 = (c & 15) * 4;
            float4 v = *(const float4*)(src + (size_t)(ti * 64 + row) * 1024 + tj * 64 + col4);
            T[col4 + 0][row] = f2bf(v.x);
            T[col4 + 1][row] = f2bf(v.y);
            T[col4 + 2][row] = f2bf(v.z);
            T[col4 + 3][row] = f2bf(v.w);
        }
        __syncthreads();
        #pragma unroll
        for (int r = 0; r < 2; ++r) {
            const int c = r * 256 + t;
            const int jrow = c >> 3, ig = (c & 7) * 8;
            bf16x8 o;
            #pragma unroll
            for (int k = 0; k < 8; ++k) o[k] = T[jrow][ig + k];
            *(bf16x8*)(dst + (size_t)(tj * 64 + jrow) * 1024 + ti * 64 + ig) = o;
        }
        return;
    }
    {                                       // ---- combined-bias path
        const int lane = t & 63;
        const int n = (bid - 12800) * 4 + (t >> 6);
        const float* row = a.wf + (size_t)n * 2048;
        float s = 0.f;
        #pragma unroll
        for (int i = 0; i < 16; ++i) s = fmaf(row[i * 64 + lane], a.bog[i * 64 + lane], s);
        #pragma unroll
        for (int i = 16; i < 32; ++i) s = fmaf(row[i * 64 + lane], a.bol[i * 64 + lane - 1024], s);
        #pragma unroll
        for (int off = 32; off > 0; off >>= 1) s += __shfl_xor(s, off, 64);
        if (lane == 0) a.cb[n] = a.bf[n] + s;
    }
}

// ---------------------------------------------------------------------------
// gemm_bk64 — 128x128 tile, BK=64 (half the barriers of the BK=32 m97 loop;
// 32 MFMA per wave per K-iter). LDS 32 KB -> ~3 blocks/CU. bf16 out.
// Column-split bias at nsplit (bias1 for nn >= nsplit).
// ---------------------------------------------------------------------------
__global__ __launch_bounds__(256, 2)
void gemm_bk64(const unsigned short* __restrict__ A, const unsigned short* __restrict__ W,
               const float* __restrict__ bias0, const float* __restrict__ bias1,
               unsigned short* __restrict__ C,
               int M, int N, int K, int lda, int ldw, int ldc, int nsplit)
{
    __shared__ __align__(16) short As[128 * 64];   // 16 KB
    __shared__ __align__(16) short Bs[128 * 64];   // 16 KB
    const int t = threadIdx.x;
    const int lane = t & 63, wave = t >> 6;
    const int wm = wave & 1, wn = wave >> 1;
    const int m0 = blockIdx.y * 128, n0 = blockIdx.x * 128;
    const int lm = lane & 15, lk = lane >> 4;

    f32x4 acc[4][4] = {};

    // chunk for thread t at round r: c = r*256 + t ; row = c>>3, kcol = (c&7)*8
    const int row0 = t >> 3, kg0 = (t & 7) * 8;
    const unsigned short* a0 = A + (size_t)(m0 + row0) * lda + kg0;
    const unsigned short* w0 = W + (size_t)(n0 + row0) * ldw + kg0;

    for (int k0 = 0; k0 < K; k0 += 64) {
        __syncthreads();
        #pragma unroll
        for (int r = 0; r < 4; ++r)
            GLD_LDS(a0 + (size_t)(r * 32) * lda + k0, As + ((size_t)(r * 256 + wave * 64)) * 8);
        #pragma unroll
        for (int r = 0; r < 4; ++r)
            GLD_LDS(w0 + (size_t)(r * 32) * ldw + k0, Bs + ((size_t)(r * 256 + wave * 64)) * 8);
        __syncthreads();

        #pragma unroll
        for (int ks = 0; ks < 2; ++ks) {
            short8 af[4], bfr[4];
            #pragma unroll
            for (int i = 0; i < 4; ++i)
                af[i] = *(const short8*)&As[(wm * 64 + i * 16 + lm) * 64 + ks * 32 + lk * 8];
            #pragma unroll
            for (int j = 0; j < 4; ++j)
                bfr[j] = *(const short8*)&Bs[(wn * 64 + j * 16 + lm) * 64 + ks * 32 + lk * 8];
            #pragma unroll
            for (int i = 0; i < 4; ++i)
                #pragma unroll
                for (int j = 0; j < 4; ++j)
                    acc[i][j] = __builtin_amdgcn_mfma_f32_16x16x32_bf16(af[i], bfr[j], acc[i][j], 0, 0, 0);
        }
    }

    #pragma unroll
    for (int i = 0; i < 4; ++i) {
        #pragma unroll
        for (int j = 0; j < 4; ++j) {
            const int nn = n0 + wn * 64 + j * 16 + lm;
            const float bv = (nn < nsplit) ? (bias0 ? bias0[nn] : 0.f)
                                           : (bias1 ? bias1[nn - nsplit] : 0.f);
            #pragma unroll
            for (int r = 0; r < 4; ++r) {
                const int mm = m0 + wm * 64 + i * 16 + lk * 4 + r;
                C[(size_t)mm * ldc + nn] = f2bf(acc[i][j][r] + bv);
            }
        }
    }
}

// ---------------------------------------------------------------------------
// gemm_m64 — 64x128 tile, BK=32 (for small-M / small-N GEMMs: 2x the blocks
// of the 128x128 tile -> >=2 blocks/CU). Wave owns 32x64; 8 MFMA/iter.
// z-batching via element offsets. OutT float (bias) or bf16.
// ---------------------------------------------------------------------------
template<typename OutT>
__global__ __launch_bounds__(256, 2)
void gemm_m64(const unsigned short* __restrict__ A, const unsigned short* __restrict__ W,
              const float* __restrict__ bias, OutT* __restrict__ C,
              int M, int N, int K, int lda, int ldw, int ldc,
              size_t sAz, size_t sWz, size_t sCz)
{
    __shared__ __align__(16) short As[64 * 32];    // 4 KB
    __shared__ __align__(16) short Bs[128 * 32];   // 8 KB
    const int z = blockIdx.z;
    A += z * sAz;  W += z * sWz;  C += z * sCz;

    const int t = threadIdx.x;
    const int lane = t & 63, wave = t >> 6;
    const int wm = wave & 1, wn = wave >> 1;
    const int m0 = blockIdx.y * 64, n0 = blockIdx.x * 128;
    const int lm = lane & 15, lk = lane >> 4;

    f32x4 acc[2][4] = {};

    const int rowA = t >> 2, kgA = (t & 3) * 8;    // A: 256 chunks, 1/thread
    const unsigned short* aptr = A + (size_t)(m0 + rowA) * lda + kgA;
    const unsigned short* wptr = W + (size_t)(n0 + rowA) * ldw + kgA;   // rounds r: +r*64 rows

    for (int k0 = 0; k0 < K; k0 += 32) {
        __syncthreads();
        GLD_LDS(aptr + k0, As + ((size_t)(wave * 64)) * 8);
        #pragma unroll
        for (int r = 0; r < 2; ++r)
            GLD_LDS(wptr + (size_t)(r * 64) * ldw + k0, Bs + ((size_t)(r * 256 + wave * 64)) * 8);
        __syncthreads();

        short8 af[2], bfr[4];
        #pragma unroll
        for (int i = 0; i < 2; ++i)
            af[i] = *(const short8*)&As[(wm * 32 + i * 16 + lm) * 32 + lk * 8];
        #pragma unroll
        for (int j = 0; j < 4; ++j)
            bfr[j] = *(const short8*)&Bs[(wn * 64 + j * 16 + lm) * 32 + lk * 8];
        #pragma unroll
        for (int i = 0; i < 2; ++i)
            #pragma unroll
            for (int j = 0; j < 4; ++j)
                acc[i][j] = __builtin_amdgcn_mfma_f32_16x16x32_bf16(af[i], bfr[j], acc[i][j], 0, 0, 0);
    }

    #pragma unroll
    for (int i = 0; i < 2; ++i) {
        #pragma unroll
        for (int j = 0; j < 4; ++j) {
            const int nn = n0 + wn * 64 + j * 16 + lm;
            const float bv = bias ? bias[nn] : 0.f;
            #pragma unroll
            for (int r = 0; r < 4; ++r) {
                const int mm = m0 + wm * 32 + i * 16 + lk * 4 + r;
                const float v = acc[i][j][r] + bv;
                const size_t idx = (size_t)mm * ldc + nn;
                if constexpr (sizeof(OutT) == 2) ((unsigned short*)C)[idx] = f2bf(v);
                else                             C[idx] = v;
            }
        }
    }
}

// ---------------------------------------------------------------------------
// V transpose (global branch): qkv_all V slice [b][s][2048 + h*64 + d]
//   -> vt[(b*NH+h)*64 + d][s].
// ---------------------------------------------------------------------------
__global__ __launch_bounds__(256)
void vt_transpose(const unsigned short* __restrict__ qkv, unsigned short* __restrict__ vt)
{
    __shared__ unsigned short Ts[64][66];
    const int t = threadIdx.x;
    const int bid = blockIdx.x;             // b*512 + h*32 + st
    const int st = bid & 31;
    const int h  = (bid >> 5) & 15;
    const int b  = bid >> 9;
    const int s0 = st * 64;

    #pragma unroll
    for (int r = 0; r < 2; ++r) {
        const int c = r * 256 + t;
        const int key = c >> 3, dg = c & 7;
        bf16x8 v = *(const bf16x8*)(qkv + ((size_t)(b * S) + s0 + key) * QS + 2 * E + h * 64 + dg * 8);
        #pragma unroll
        for (int j = 0; j < 8; ++j) Ts[dg * 8 + j][key] = v[j];
    }
    __syncthreads();
    #pragma unroll
    for (int r = 0; r < 2; ++r) {
        const int c = r * 256 + t;
        const int d = c >> 3, kg = c & 7;
        bf16x8 o;
        #pragma unroll
        for (int j = 0; j < 8; ++j) o[j] = Ts[d][kg * 8 + j];
        *(bf16x8*)(vt + ((size_t)(b * NH + h) * 64 + d) * S + s0 + kg * 8) = o;
    }
}

// ---------------------------------------------------------------------------
// MFMA flash attention v3 (verified R6/R7): operand-swapped, 2 q-groups/wave.
// Writes into attn_cat [4096][2048], global half (cols h*64, row stride 2048).
// ---------------------------------------------------------------------------
__global__ __launch_bounds__(256, 2)
void attn_flash(const unsigned short* __restrict__ qkv,
                const unsigned short* __restrict__ vt,
                unsigned short* __restrict__ attn)
{
    __shared__ __align__(16) unsigned short Ks[2][64][32];    // 8 KB
    __shared__ __align__(16) unsigned short Vs[2][64][32];    // 8 KB
    __shared__ __align__(16) unsigned short Pt[4][2][16][64]; // 16 KB

    const int t = threadIdx.x, lane = t & 63, wq = t >> 6;
    const int lm = lane & 15, lk = lane >> 4;
    const int bid = blockIdx.x;              // b*256 + h*16 + qb
    const int qb = bid & 15;
    const int h  = (bid >> 4) & 15;
    const int b  = bid >> 8;
    const int q0 = qb * 128 + wq * 32;       // wave's first query

    short8 qf[2][2];
    #pragma unroll
    for (int qg = 0; qg < 2; ++qg) {
        const unsigned short* qrow = qkv + ((size_t)(b * S) + q0 + qg * 16 + lm) * QS + h * DH;
        #pragma unroll
        for (int kk = 0; kk < 2; ++kk) {
            bf16x8 v = *(const bf16x8*)(qrow + kk * 32 + lk * 8);
            #pragma unroll
            for (int j = 0; j < 8; ++j)
                ((unsigned short*)&qf[qg][kk])[j] = f2bf(bf2f(v[j]) * 0.125f);
        }
    }

    const int row0 = t >> 2;
    const int sw0 = (row0 ^ (row0 >> 2)) & 3;
    const int g0 = ((t & 3) ^ sw0) * 8;
    const unsigned short* kg[2];
    const unsigned short* vg[2];
    #pragma unroll
    for (int r = 0; r < 2; ++r) {
        kg[r] = qkv + ((size_t)(b * S) + row0) * QS + E + h * 64 + r * 32 + g0;
        vg[r] = vt + ((size_t)(b * NH + h) * 64 + row0) * S + r * 32 + g0;
    }
    unsigned short* kl[2] = { &Ks[0][0][0] + (wq * 64) * 8, &Ks[0][0][0] + (256 + wq * 64) * 8 };
    unsigned short* vl[2] = { &Vs[0][0][0] + (wq * 64) * 8, &Vs[0][0][0] + (256 + wq * 64) * 8 };

    f32x4 O[2][4] = {};
    float m[2] = { -INFINITY, -INFINITY };
    float l[2] = { 0.f, 0.f };
    const int sw = lm & 7;
    const int fr = (lm ^ (lm >> 2)) & 3;

    for (int kt = 0; kt < S / 64; ++kt) {
        __syncthreads();
        GLD_LDS(kg[0] + (size_t)kt * 64 * QS, kl[0]);
        GLD_LDS(kg[1] + (size_t)kt * 64 * QS, kl[1]);
        GLD_LDS(vg[0] + kt * 64, vl[0]);
        GLD_LDS(vg[1] + kt * 64, vl[1]);
        __syncthreads();

        f32x4 st[2][4] = {};
        #pragma unroll
        for (int jn = 0; jn < 4; ++jn) {
            #pragma unroll
            for (int kk = 0; kk < 2; ++kk) {
                short8 kf = *(const short8*)&Ks[kk][jn * 16 + lm][(lk ^ fr) * 8];
                #pragma unroll
                for (int qg = 0; qg < 2; ++qg)
                    st[qg][jn] = __builtin_amdgcn_mfma_f32_16x16x32_bf16(kf, qf[qg][kk], st[qg][jn], 0, 0, 0);
            }
        }

        float alpha[2];
        #pragma unroll
        for (int qg = 0; qg < 2; ++qg) {
            float vmax = st[qg][0][0];
            #pragma unroll
            for (int jn = 0; jn < 4; ++jn)
                #pragma unroll
                for (int g = 0; g < 4; ++g) vmax = fmaxf(vmax, st[qg][jn][g]);
            vmax = fmaxf(vmax, __shfl_xor(vmax, 16, 64));
            vmax = fmaxf(vmax, __shfl_xor(vmax, 32, 64));
            const float mn = fmaxf(m[qg], vmax);
            alpha[qg] = __expf(m[qg] - mn);
            m[qg] = mn;
            float vsum = 0.f;
            #pragma unroll
            for (int jn = 0; jn < 4; ++jn)
                #pragma unroll
                for (int g = 0; g < 4; ++g) {
                    const float p = __expf(st[qg][jn][g] - mn);
                    st[qg][jn][g] = p;
                    vsum += p;
                }
            vsum += __shfl_xor(vsum, 16, 64);
            vsum += __shfl_xor(vsum, 32, 64);
            l[qg] = l[qg] * alpha[qg] + vsum;
        }

        #pragma unroll
        for (int qg = 0; qg < 2; ++qg)
            #pragma unroll
            for (int jn = 0; jn < 4; ++jn) {
                const int cc = ((jn * 2 + (lk >> 1)) ^ sw) * 8 + (lk & 1) * 4;
                pack4_store(&Pt[wq][qg][lm][cc],
                            st[qg][jn][0], st[qg][jn][1], st[qg][jn][2], st[qg][jn][3]);
            }

        #pragma unroll
        for (int qg = 0; qg < 2; ++qg)
            #pragma unroll
            for (int jd = 0; jd < 4; ++jd)
                #pragma unroll
                for (int g = 0; g < 4; ++g) O[qg][jd][g] *= alpha[qg];

        short8 pf[2][2];
        #pragma unroll
        for (int qg = 0; qg < 2; ++qg) {
            pf[qg][0] = *(const short8*)&Pt[wq][qg][lm][((lk + 0) ^ sw) * 8];
            pf[qg][1] = *(const short8*)&Pt[wq][qg][lm][((lk + 4) ^ sw) * 8];
        }
        #pragma unroll
        for (int jd = 0; jd < 4; ++jd) {
            #pragma unroll
            for (int kk = 0; kk < 2; ++kk) {
                short8 vf = *(const short8*)&Vs[kk][jd * 16 + lm][(lk ^ fr) * 8];
                #pragma unroll
                for (int qg = 0; qg < 2; ++qg)
                    O[qg][jd] = __builtin_amdgcn_mfma_f32_16x16x32_bf16(vf, pf[qg][kk], O[qg][jd], 0, 0, 0);
            }
        }
    }

    #pragma unroll
    for (int qg = 0; qg < 2; ++qg) {
        const float inv = 1.0f / l[qg];
        unsigned short* orow = attn + ((size_t)(b * S) + q0 + qg * 16 + lm) * 2048 + h * 64;
        #pragma unroll
        for (int jd = 0; jd < 4; ++jd)
            pack4_store(orow + jd * 16 + lk * 4,
                        O[qg][jd][0] * inv, O[qg][jd][1] * inv,
                        O[qg][jd][2] * inv, O[qg][jd][3] * inv);
    }
}

// ---------------------------------------------------------------------------
// Block-local attention (16-key blocks). Wave per query, lane = d.
// Writes into attn_cat local half (cols 1024 + h*64, row stride 2048).
// ---------------------------------------------------------------------------
__global__ __launch_bounds__(256)
void attn_local(const unsigned short* __restrict__ qkvl, unsigned short* __restrict__ outp)
{
    const int t = threadIdx.x, lane = t & 63;
    const int gid = blockIdx.x * 4 + (t >> 6);
    const int q = gid & (S - 1);
    const int h = (gid >> 11) & (NH - 1);
    const int b = gid >> 15;

    const unsigned short* base = qkvl + (size_t)b * S * QS;
    const float qd = bf2f(base[(size_t)q * QS + h * DH + lane]) * 0.125f;
    const int j0 = q & ~15;

    float s[16];
    #pragma unroll
    for (int jj = 0; jj < 16; ++jj) {
        const float kd = bf2f(base[(size_t)(j0 + jj) * QS + E + h * DH + lane]);
        float ps = qd * kd;
        #pragma unroll
        for (int off = 32; off > 0; off >>= 1)
            ps += __shfl_xor(ps, off, 64);
        s[jj] = ps;
    }
    float mx = s[0];
    #pragma unroll
    for (int jj = 1; jj < 16; ++jj) mx = fmaxf(mx, s[jj]);
    float l = 0.f;
    #pragma unroll
    for (int jj = 0; jj < 16; ++jj) { s[jj] = __expf(s[jj] - mx); l += s[jj]; }
    float o = 0.f;
    #pragma unroll
    for (int jj = 0; jj < 16; ++jj) {
        const float vd = bf2f(base[(size_t)(j0 + jj) * QS + 2 * E + h * DH + lane]);
        o = fmaf(s[jj], vd, o);
    }
    outp[(size_t)(b * S + q) * 2048 + 1024 + h * DH + lane] = f2bf(o / l);
}

// ---------------------------------------------------------------------------
extern "C" void kernel_launch(void* const* d_in, const int* in_sizes, int n_in,
                              void* d_out, int out_size, void* d_ws, size_t ws_size,
                              hipStream_t stream)
{
    const float* x       = (const float*)d_in[0];
    const float* w_in_g  = (const float*)d_in[1];
    const float* b_in_g  = (const float*)d_in[2];
    const float* w_out_g = (const float*)d_in[3];
    const float* b_out_g = (const float*)d_in[4];
    const float* w_in_l  = (const float*)d_in[5];
    const float* b_in_l  = (const float*)d_in[6];
    const float* w_out_l = (const float*)d_in[7];
    const float* b_out_l = (const float*)d_in[8];
    const float* w_f     = (const float*)d_in[9];
    const float* b_f     = (const float*)d_in[10];
    float* out = (float*)d_out;

    const int M = Bz * S;   // 4096
    char* p = (char*)d_ws;
    unsigned short* xb       = (unsigned short*)p; p += (size_t)M * 1024 * 2;        //  8 MB
    unsigned short* qkv_all  = (unsigned short*)p; p += (size_t)M * QS * 2;          // 48 MB
    unsigned short* attn_cat = (unsigned short*)p; p += (size_t)M * 2048 * 2;        // 16 MB
    unsigned short* win_all  = (unsigned short*)p; p += (size_t)6144 * 1024 * 2;     // 12 MB
    unsigned short* wf_b     = (unsigned short*)p; p += (size_t)1024 * 2048 * 2;     //  4 MB
    unsigned short* woutT    = (unsigned short*)p; p += (size_t)2 * 1024 * 1024 * 2; //  4 MB
    unsigned short* wcomb    = (unsigned short*)p; p += (size_t)1024 * 2048 * 2;     //  4 MB
    unsigned short* vtbuf    = (unsigned short*)p; p += (size_t)Bz * NH * 64 * S * 2;//  8 MB
    float*          cb       = (float*)p;          p += 1024 * 4;

    dim3 blk(256);

    // 1) all preprocessing in one launch (cvt x4 regions + w_out transposes + cb).
    PrepArgs pa;
    pa.csrc[0] = x;      pa.cdst[0] = xb;                    pa.cn[0] = M * 1024;
    pa.csrc[1] = w_in_g; pa.cdst[1] = win_all;               pa.cn[1] = 3072 * 1024;
    pa.csrc[2] = w_in_l; pa.cdst[2] = win_all + 3072 * 1024; pa.cn[2] = 3072 * 1024;
    pa.csrc[3] = w_f;    pa.cdst[3] = wf_b;                  pa.cn[3] = 1024 * 2048;
    pa.wog = w_out_g; pa.wol = w_out_l;
    pa.wogT = woutT;  pa.wolT = woutT + 1024 * 1024;
    pa.wf = w_f; pa.bf = b_f; pa.bog = b_out_g; pa.bol = b_out_l; pa.cb = cb;
    prep_all<<<dim3(13056), blk, 0, stream>>>(pa);

    // 2) Wcomb_z[n,k] = wf[:, z*1024:]@w_out_z -> wcomb [1024][2048] bf16.
    gemm_m64<unsigned short><<<dim3(8, 16, 2), blk, 0, stream>>>(
        wf_b, woutT, nullptr, wcomb,
        1024, 1024, 1024, 2048, 1024, 2048,
        1024, (size_t)1024 * 1024, 1024);

    // 3) Combined QKV GEMM: [4096,1024] @ [6144,1024]^T -> qkv_all [4096,6144]
    gemm_bk64<<<dim3(6144 / 128, M / 128), blk, 0, stream>>>(
        xb, win_all, b_in_g, b_in_l, qkv_all,
        M, 6144, 1024, 1024, 1024, QS, 3072);

    // 4) attention
    vt_transpose<<<dim3(Bz * NH * 32), blk, 0, stream>>>(qkv_all, vtbuf);
    attn_flash<<<dim3(Bz * NH * (S / 128)), blk, 0, stream>>>(qkv_all, vtbuf, attn_cat);
    attn_local<<<dim3(Bz * NH * S / 4), blk, 0, stream>>>(qkv_all + 3072, attn_cat);

    // 5) Fused tail: out = attn_cat [4096,2048] @ wcomb[1024,2048]^T + cb (fp32).
    gemm_m64<float><<<dim3(1024 / 128, M / 64, 1), blk, 0, stream>>>(
        attn_cat, wcomb, cb, out,
        M, 1024, 2048, 2048, 2048, 1024,
        0, 0, 0);
}